// Round 2
// baseline (4239.890 us; speedup 1.0000x reference)
//
#include <hip/hip_runtime.h>
#include <hip/hip_bf16.h>
#include <math.h>

#define T_TOKENS 100352

// Map window-layout row r (widx*98 + n) to flat token index in (B,D,H,W) space.
// For the shifted block, gather (LN side) and scatter (proj side) use the SAME
// mapping: source coord sd=(d+1)%16, sh=(h+3)%56, sw=(w+3)%56.
__device__ __forceinline__ int win_row_to_token(int r, int shifted) {
    int widx = r / 98;
    int n = r - widx * 98;
    int b = widx >> 9;          // 512 windows per batch
    int remw = widx & 511;
    int dW = remw >> 6;
    int hW = (remw >> 3) & 7;
    int wW = remw & 7;
    int zd = n / 49;
    int nr = n - zd * 49;
    int zh = nr / 7;
    int zw = nr - zh * 7;
    int d = dW * 2 + zd;
    int h = hW * 7 + zh;
    int w = wW * 7 + zw;
    if (shifted) {
        d = (d + 1) & 15;
        h += 3; if (h >= 56) h -= 56;
        w += 3; if (w >= 56) w -= 56;
    }
    return ((b * 16 + d) * 56 + h) * 56 + w;
}

// LayerNorm over C=192. mode: 0 = linear (token = row_off + r),
// 1 = window gather (no shift), 2 = window gather (shifted).
// One wave per output row; lane handles channels {l, l+64, l+128}.
// Writes to LOCAL row r of out.
__global__ __launch_bounds__(256) void ln_kernel(
    const float* __restrict__ x, const float* __restrict__ g,
    const float* __restrict__ b, float* __restrict__ out, int mode, int row_off)
{
    int r = blockIdx.x * 4 + (threadIdx.x >> 6);
    int lane = threadIdx.x & 63;
    int t = (mode == 0) ? (row_off + r) : win_row_to_token(row_off + r, mode == 2);
    const float* xp = x + (size_t)t * 192;
    float v0 = xp[lane], v1 = xp[lane + 64], v2 = xp[lane + 128];
    float s = v0 + v1 + v2;
    float sq = v0 * v0 + v1 * v1 + v2 * v2;
    #pragma unroll
    for (int off = 32; off; off >>= 1) {
        s += __shfl_xor(s, off);
        sq += __shfl_xor(sq, off);
    }
    float mu = s * (1.0f / 192.0f);
    float var = sq * (1.0f / 192.0f) - mu * mu;
    float rs = rsqrtf(var + 1e-5f);
    float* op = out + (size_t)r * 192;
    op[lane]       = (v0 - mu) * rs * g[lane]       + b[lane];
    op[lane + 64]  = (v1 - mu) * rs * g[lane + 64]  + b[lane + 64];
    op[lane + 128] = (v2 - mu) * rs * g[lane + 128] + b[lane + 128];
}

// out[M,N] = A[M,K] @ Wt[N,K]^T + bias.
// ep 0: plain bias (local out rows, stride N)
// ep 1: bias + exact GELU (local out rows, stride N)
// ep 2: bias + residual, scattered via win_row_to_token(row_off + r) (global out/resx)
// ep 3: bias + residual, linear local rows (out/resx pre-offset by caller)
__global__ __launch_bounds__(256) void gemm_kernel(
    const float* __restrict__ A, const float* __restrict__ Wt,
    const float* __restrict__ bias, float* out,
    const float* resx, int M, int N, int K, int ep, int shifted, int row_off)
{
    __shared__ __align__(16) float As[64][68];
    __shared__ __align__(16) float Bs[64][68];
    const int ntiles = N >> 6;
    const int bm = blockIdx.x / ntiles;
    const int bn = blockIdx.x - bm * ntiles;
    const int r0 = bm << 6, n0 = bn << 6;
    const int tid = threadIdx.x;
    const int lr = tid >> 4, lc = tid & 15;
    float acc[4][4] = {{0.f}};
    for (int k0 = 0; k0 < K; k0 += 64) {
        #pragma unroll
        for (int it = 0; it < 4; ++it) {
            int r = lr + (it << 4);
            int kb = lc << 2;
            float4 a = *(const float4*)&A[(size_t)(r0 + r) * K + k0 + kb];
            As[kb + 0][r] = a.x; As[kb + 1][r] = a.y;
            As[kb + 2][r] = a.z; As[kb + 3][r] = a.w;
            float4 bb = *(const float4*)&Wt[(size_t)(n0 + r) * K + k0 + kb];
            Bs[kb + 0][r] = bb.x; Bs[kb + 1][r] = bb.y;
            Bs[kb + 2][r] = bb.z; Bs[kb + 3][r] = bb.w;
        }
        __syncthreads();
        #pragma unroll 8
        for (int kk = 0; kk < 64; ++kk) {
            float4 af = *(const float4*)&As[kk][lr << 2];
            float4 bf = *(const float4*)&Bs[kk][lc << 2];
            float av[4] = {af.x, af.y, af.z, af.w};
            float bv[4] = {bf.x, bf.y, bf.z, bf.w};
            #pragma unroll
            for (int ii = 0; ii < 4; ++ii)
                #pragma unroll
                for (int jj = 0; jj < 4; ++jj)
                    acc[ii][jj] = fmaf(av[ii], bv[jj], acc[ii][jj]);
        }
        __syncthreads();
    }
    if (ep <= 1) {
        #pragma unroll
        for (int ii = 0; ii < 4; ++ii) {
            size_t row = (size_t)(r0 + (lr << 2) + ii);
            #pragma unroll
            for (int jj = 0; jj < 4; ++jj) {
                int c = n0 + (lc << 2) + jj;
                float v = acc[ii][jj] + bias[c];
                if (ep == 1) v = 0.5f * v * (1.0f + erff(v * 0.70710678118654752f));
                out[row * N + c] = v;
            }
        }
    } else {
        #pragma unroll
        for (int ii = 0; ii < 4; ++ii) {
            int r = r0 + (lr << 2) + ii;
            int t = (ep == 2) ? win_row_to_token(row_off + r, shifted) : r;
            size_t base = (size_t)t * 192;
            #pragma unroll
            for (int jj = 0; jj < 4; ++jj) {
                int c = n0 + (lc << 2) + jj;
                out[base + c] = resx[base + c] + acc[ii][jj] + bias[c];
            }
        }
    }
}

// One block per (local window, head). qkv: local [CR,576] laid out q|k|v each [6][32].
// Writes attn-out into LOCAL rows of out (stride 192).
__global__ __launch_bounds__(256) void attn_kernel(
    const float* __restrict__ qkv, const float* __restrict__ table,
    float* __restrict__ out, int shifted, int widx_off)
{
    __shared__ __align__(16) float qs[98 * 32];
    __shared__ __align__(16) float ks[98 * 36];   // padded stride 36 (bank spread)
    __shared__ __align__(16) float vs[98 * 32];
    __shared__ __align__(16) float sc[98 * 100];
    const int wloc = blockIdx.x;
    const int head = blockIdx.y;
    const int tid = threadIdx.x;
    const int r0 = wloc * 98;                      // local row base
    const float scale = 0.17677669529663687f;      // 32^-0.5

    for (int idx = tid; idx < 3136; idx += 256) {
        int n = idx >> 5, dd = idx & 31;
        size_t base = (size_t)(r0 + n) * 576 + head * 32 + dd;
        qs[idx] = qkv[base] * scale;
        ks[n * 36 + dd] = qkv[base + 192];
        vs[idx] = qkv[base + 384];
    }
    __syncthreads();

    int remw = (widx_off + wloc) & 511;            // mask-window id (per batch)
    int dW = remw >> 6, hW = (remw >> 3) & 7, wW = remw & 7;

    for (int idx = tid; idx < 9604; idx += 256) {
        int n = idx / 98, m = idx - n * 98;
        const float4* qp = (const float4*)(qs + n * 32);
        const float4* kp = (const float4*)(ks + m * 36);
        float acc = 0.f;
        #pragma unroll
        for (int q8 = 0; q8 < 8; ++q8) {
            float4 a = qp[q8], b2 = kp[q8];
            acc += a.x * b2.x + a.y * b2.y + a.z * b2.z + a.w * b2.w;
        }
        // relative position bias (computed arithmetically, no RPI table)
        int zd = n / 49, nr = n - zd * 49, zh = nr / 7, zw = nr - zh * 7;
        int yd = m / 49, mr = m - yd * 49, yh = mr / 7, yw = mr - yh * 7;
        int rpi = (zd - yd + 1) * 169 + (zh - yh + 6) * 13 + (zw - yw + 6);
        acc += table[rpi * 6 + head];
        if (shifted) {
            // region ids on the rolled grid; reference ADDS 2.0 on cross-region pairs
            int d1 = dW * 2 + zd, h1 = hW * 7 + zh, w1 = wW * 7 + zw;
            int d2 = dW * 2 + yd, h2 = hW * 7 + yh, w2 = wW * 7 + yw;
            int c1 = (d1 < 14 ? 0 : (d1 < 15 ? 1 : 2)) * 9
                   + (h1 < 49 ? 0 : (h1 < 53 ? 1 : 2)) * 3
                   + (w1 < 49 ? 0 : (w1 < 53 ? 1 : 2));
            int c2 = (d2 < 14 ? 0 : (d2 < 15 ? 1 : 2)) * 9
                   + (h2 < 49 ? 0 : (h2 < 53 ? 1 : 2)) * 3
                   + (w2 < 49 ? 0 : (w2 < 53 ? 1 : 2));
            if (c1 != c2) acc += 2.0f;
        }
        sc[n * 100 + m] = acc;
    }
    __syncthreads();

    // softmax: one wave per row
    int wid = tid >> 6, lane = tid & 63;
    for (int n = wid; n < 98; n += 4) {
        float* row = sc + n * 100;
        float v0 = row[lane];
        float v1 = (lane < 34) ? row[64 + lane] : -3.0e30f;
        float mx = fmaxf(v0, v1);
        #pragma unroll
        for (int off = 32; off; off >>= 1) mx = fmaxf(mx, __shfl_xor(mx, off));
        float e0 = expf(v0 - mx);
        float e1 = (lane < 34) ? expf(v1 - mx) : 0.f;
        float s = e0 + e1;
        #pragma unroll
        for (int off = 32; off; off >>= 1) s += __shfl_xor(s, off);
        float inv = 1.0f / s;
        row[lane] = e0 * inv;
        if (lane < 34) row[64 + lane] = e1 * inv;
    }
    __syncthreads();

    // out = attn @ v  (local rows, stride 192)
    for (int idx = tid; idx < 3136; idx += 256) {
        int n = idx >> 5, dd = idx & 31;
        const float* row = sc + n * 100;
        float acc = 0.f;
        for (int m = 0; m < 98; ++m) acc += row[m] * vs[m * 32 + dd];
        out[(size_t)(r0 + n) * 192 + head * 32 + dd] = acc;
    }
}

extern "C" void kernel_launch(void* const* d_in, const int* in_sizes, int n_in,
                              void* d_out, int out_size, void* d_ws, size_t ws_size,
                              hipStream_t stream) {
    (void)in_sizes; (void)n_in; (void)out_size;
    const float* x      = (const float*)d_in[0];
    const float* ln1_g  = (const float*)d_in[1];
    const float* ln1_b  = (const float*)d_in[2];
    const float* qkv_w  = (const float*)d_in[3];
    const float* qkv_b  = (const float*)d_in[4];
    const float* proj_w = (const float*)d_in[5];
    const float* proj_b = (const float*)d_in[6];
    const float* table  = (const float*)d_in[7];
    const float* ln2_g  = (const float*)d_in[8];
    const float* ln2_b  = (const float*)d_in[9];
    const float* fc1_w  = (const float*)d_in[10];
    const float* fc1_b  = (const float*)d_in[11];
    const float* fc2_w  = (const float*)d_in[12];
    const float* fc2_b  = (const float*)d_in[13];
    float* out = (float*)d_out;

    // Adaptive chunking over windows so scratch fits ws_size.
    // Per chunk: bufA (CR x 192 f32) + bufQ (CR x 768 f32), CR = 98*wpc.
    const size_t per_win_bytes = 98ull * (192 + 768) * sizeof(float);
    int wpc = 32;
    const int cands[6] = {1024, 512, 256, 128, 64, 32};
    for (int ci = 0; ci < 6; ++ci) {
        if ((size_t)cands[ci] * per_win_bytes <= ws_size) { wpc = cands[ci]; break; }
    }
    const int NC = 1024 / wpc;
    const int CR = 98 * wpc;                 // chunk rows (multiple of 64 for wpc>=32)
    float* bufA = (float*)d_ws;              // CR x 192
    float* bufQ = bufA + (size_t)CR * 192;   // CR x 768 (qkv uses 576, fc1 uses 768)

    for (int i = 0; i < 2; ++i) {
        const int shifted = (i == 1);
        const float* xsrc = (i == 0) ? x : out;
        // ---- attention phase (chunked over windows) ----
        for (int c = 0; c < NC; ++c) {
            const int row_off = c * CR;
            const int widx_off = c * wpc;
            ln_kernel<<<CR / 4, 256, 0, stream>>>(
                xsrc, ln1_g + i * 192, ln1_b + i * 192, bufA, shifted ? 2 : 1, row_off);
            gemm_kernel<<<(CR / 64) * 9, 256, 0, stream>>>(
                bufA, qkv_w + (size_t)i * 576 * 192, qkv_b + i * 576,
                bufQ, nullptr, CR, 576, 192, 0, 0, 0);
            attn_kernel<<<dim3(wpc, 6), 256, 0, stream>>>(
                bufQ, table + i * 3042, bufA, shifted, widx_off);
            gemm_kernel<<<(CR / 64) * 3, 256, 0, stream>>>(
                bufA, proj_w + (size_t)i * 192 * 192, proj_b + i * 192,
                out, xsrc, CR, 192, 192, 2, shifted, row_off);
        }
        // ---- MLP phase (chunked over token rows) ----
        for (int c = 0; c < NC; ++c) {
            const int row_off = c * CR;
            ln_kernel<<<CR / 4, 256, 0, stream>>>(
                out, ln2_g + i * 192, ln2_b + i * 192, bufA, 0, row_off);
            gemm_kernel<<<(CR / 64) * 12, 256, 0, stream>>>(
                bufA, fc1_w + (size_t)i * 768 * 192, fc1_b + i * 768,
                bufQ, nullptr, CR, 768, 192, 1, 0, 0);
            gemm_kernel<<<(CR / 64) * 3, 256, 0, stream>>>(
                bufQ, fc2_w + (size_t)i * 192 * 768, fc2_b + i * 192,
                out + (size_t)row_off * 192, out + (size_t)row_off * 192,
                CR, 192, 768, 3, 0, 0);
        }
    }
}

// Round 3
// 1754.263 us; speedup vs baseline: 2.4169x; 2.4169x over previous
//
#include <hip/hip_runtime.h>
#include <math.h>

#define T_TOKENS 100352

typedef short s16x8 __attribute__((ext_vector_type(8)));
typedef float f32x4 __attribute__((ext_vector_type(4)));

__device__ __forceinline__ unsigned short f2b(float f) {
    union { float f; unsigned u; } x; x.f = f;
    unsigned r = x.u + 0x7fffu + ((x.u >> 16) & 1u);   // RNE
    return (unsigned short)(r >> 16);
}
__device__ __forceinline__ float b2f(unsigned short h) {
    union { unsigned u; float f; } x; x.u = (unsigned)h << 16;
    return x.f;
}

#define GLOAD_LDS16(gsrc, ldst) __builtin_amdgcn_global_load_lds( \
    (const __attribute__((address_space(1))) void*)(gsrc), \
    (__attribute__((address_space(3))) void*)(ldst), 16, 0, 0)

// Map window-layout row r (widx*98 + n) to flat token index. Self-inverse
// pairing: gather (LN) and scatter (proj) use the same mapping.
__device__ __forceinline__ int win_row_to_token(int r, int shifted) {
    int widx = r / 98;
    int n = r - widx * 98;
    int b = widx >> 9;
    int remw = widx & 511;
    int dW = remw >> 6, hW = (remw >> 3) & 7, wW = remw & 7;
    int zd = n / 49;
    int nr = n - zd * 49;
    int zh = nr / 7, zw = nr - zh * 7;
    int d = dW * 2 + zd, h = hW * 7 + zh, w = wW * 7 + zw;
    if (shifted) {
        d = (d + 1) & 15;
        h += 3; if (h >= 56) h -= 56;
        w += 3; if (w >= 56) w -= 56;
    }
    return ((b * 16 + d) * 56 + h) * 56 + w;
}

__global__ __launch_bounds__(256) void f2b_kernel(
    const float* __restrict__ in, unsigned short* __restrict__ out, int n)
{
    int i = blockIdx.x * 256 + threadIdx.x;
    if (i < n) out[i] = f2b(in[i]);
}

// LayerNorm over C=192 -> bf16 out. mode 0: linear; 1: window gather; 2: shifted gather.
__global__ __launch_bounds__(256) void ln_kernel(
    const float* __restrict__ x, const float* __restrict__ g,
    const float* __restrict__ b, unsigned short* __restrict__ out, int mode, int row_off)
{
    int r = blockIdx.x * 4 + (threadIdx.x >> 6);
    int lane = threadIdx.x & 63;
    int t = (mode == 0) ? (row_off + r) : win_row_to_token(row_off + r, mode == 2);
    const float* xp = x + (size_t)t * 192;
    float v0 = xp[lane], v1 = xp[lane + 64], v2 = xp[lane + 128];
    float s = v0 + v1 + v2;
    float sq = v0 * v0 + v1 * v1 + v2 * v2;
    #pragma unroll
    for (int off = 32; off; off >>= 1) {
        s += __shfl_xor(s, off);
        sq += __shfl_xor(sq, off);
    }
    float mu = s * (1.0f / 192.0f);
    float var = sq * (1.0f / 192.0f) - mu * mu;
    float rs = rsqrtf(var + 1e-5f);
    unsigned short* op = out + (size_t)r * 192;
    op[lane]       = f2b((v0 - mu) * rs * g[lane]       + b[lane]);
    op[lane + 64]  = f2b((v1 - mu) * rs * g[lane + 64]  + b[lane + 64]);
    op[lane + 128] = f2b((v2 - mu) * rs * g[lane + 128] + b[lane + 128]);
}

// bf16 MFMA GEMM: out[M,N] = A[M,K] @ Wb[N,K]^T + bias.
// Tile 128x64, BK=64, 4 waves in 2x2 (each wave 64x32). XOR-swizzled LDS
// (st-pattern) fed by pre-swizzled global_load_lds sources (linear LDS dest).
// ep 0: bias -> bf16 out          ep 1: bias+GELU -> bf16 out
// ep 2: bias+residual scatter (win_row_to_token) -> f32 out
// ep 3: bias+residual linear local rows -> f32 out
__global__ __launch_bounds__(256) void gemm_kernel(
    const unsigned short* __restrict__ A, const unsigned short* __restrict__ Wb,
    const float* __restrict__ bias, void* outp, const float* resx,
    int N, int K, int ep, int shifted, int row_off)
{
    __shared__ short As[128 * 64];
    __shared__ short Bs[64 * 64];
    const int ntiles = N >> 6;
    const int bm = blockIdx.x / ntiles;
    const int bn = blockIdx.x - bm * ntiles;
    const int r0 = bm << 7, n0 = bn << 6;
    const int tid = threadIdx.x;
    const int wid = tid >> 6, lane = tid & 63;
    const int wrow = (wid >> 1) << 6;   // 0 / 64
    const int wcol = (wid & 1) << 5;    // 0 / 32
    const int srow = lane >> 3;         // row within 8-row staging group
    const int sslot = lane & 7;         // 16B slot within 128B row

    f32x4 acc[4][2];
    #pragma unroll
    for (int mi = 0; mi < 4; ++mi)
        #pragma unroll
        for (int ni = 0; ni < 2; ++ni)
            acc[mi][ni] = (f32x4){0.f, 0.f, 0.f, 0.f};

    for (int k0 = 0; k0 < K; k0 += 64) {
        // A-tile: wave stages rows wid*32 .. wid*32+31 (4 groups of 8 rows)
        #pragma unroll
        for (int g = 0; g < 4; ++g) {
            int row = wid * 32 + g * 8 + srow;
            const unsigned short* src =
                A + (size_t)(r0 + row) * K + k0 + ((sslot ^ (row & 7)) << 3);
            GLOAD_LDS16(src, &As[(wid * 32 + g * 8) * 64]);
        }
        // B-tile: wave stages rows wid*16 .. wid*16+15 (2 groups)
        #pragma unroll
        for (int g = 0; g < 2; ++g) {
            int row = wid * 16 + g * 8 + srow;
            const unsigned short* src =
                Wb + (size_t)(n0 + row) * K + k0 + ((sslot ^ (row & 7)) << 3);
            GLOAD_LDS16(src, &Bs[(wid * 16 + g * 8) * 64]);
        }
        __syncthreads();
        #pragma unroll
        for (int ks = 0; ks < 2; ++ks) {
            const int q = ks * 4 + (lane >> 4);       // 16B k-slot 0..7
            s16x8 bfr[2];
            #pragma unroll
            for (int ni = 0; ni < 2; ++ni) {
                int col = wcol + ni * 16 + (lane & 15);
                bfr[ni] = *(const s16x8*)&Bs[col * 64 + ((q ^ (col & 7)) << 3)];
            }
            #pragma unroll
            for (int mi = 0; mi < 4; ++mi) {
                int row = wrow + mi * 16 + (lane & 15);
                s16x8 afr = *(const s16x8*)&As[row * 64 + ((q ^ (row & 7)) << 3)];
                #pragma unroll
                for (int ni = 0; ni < 2; ++ni)
                    acc[mi][ni] = __builtin_amdgcn_mfma_f32_16x16x32_bf16(
                        afr, bfr[ni], acc[mi][ni], 0, 0, 0);
            }
        }
        __syncthreads();
    }

    // Epilogue. C/D layout: col = lane&15, row = (lane>>4)*4 + reg.
    #pragma unroll
    for (int mi = 0; mi < 4; ++mi) {
        #pragma unroll
        for (int ni = 0; ni < 2; ++ni) {
            int colg = n0 + wcol + ni * 16 + (lane & 15);
            float bv = bias[colg];
            #pragma unroll
            for (int rg = 0; rg < 4; ++rg) {
                int rowl = r0 + wrow + mi * 16 + ((lane >> 4) << 2) + rg;
                float v = acc[mi][ni][rg] + bv;
                if (ep == 0) {
                    ((unsigned short*)outp)[(size_t)rowl * N + colg] = f2b(v);
                } else if (ep == 1) {
                    v = 0.5f * v * (1.0f + erff(v * 0.70710678118654752f));
                    ((unsigned short*)outp)[(size_t)rowl * N + colg] = f2b(v);
                } else {
                    int t = (ep == 2) ? win_row_to_token(row_off + rowl, shifted) : rowl;
                    size_t o = (size_t)t * 192 + colg;
                    ((float*)outp)[o] = resx[o] + v;
                }
            }
        }
    }
}

// One block per (local window, head). qkv: local [CR,576] bf16, q|k|v each [6][32].
__global__ __launch_bounds__(256) void attn_kernel(
    const unsigned short* __restrict__ qkv, const float* __restrict__ table,
    unsigned short* __restrict__ out, int shifted, int widx_off)
{
    __shared__ __align__(16) float qs[98 * 32];
    __shared__ __align__(16) float ks[98 * 36];
    __shared__ __align__(16) float vs[98 * 32];
    __shared__ __align__(16) float sc[98 * 100];
    const int wloc = blockIdx.x;
    const int head = blockIdx.y;
    const int tid = threadIdx.x;
    const int r0 = wloc * 98;
    const float scale = 0.17677669529663687f;

    for (int idx = tid; idx < 3136; idx += 256) {
        int n = idx >> 5, dd = idx & 31;
        size_t base = (size_t)(r0 + n) * 576 + head * 32 + dd;
        qs[idx] = b2f(qkv[base]) * scale;
        ks[n * 36 + dd] = b2f(qkv[base + 192]);
        vs[idx] = b2f(qkv[base + 384]);
    }
    __syncthreads();

    int remw = (widx_off + wloc) & 511;
    int dW = remw >> 6, hW = (remw >> 3) & 7, wW = remw & 7;

    for (int idx = tid; idx < 9604; idx += 256) {
        int n = idx / 98, m = idx - n * 98;
        const float4* qp = (const float4*)(qs + n * 32);
        const float4* kp = (const float4*)(ks + m * 36);
        float acc = 0.f;
        #pragma unroll
        for (int q8 = 0; q8 < 8; ++q8) {
            float4 a = qp[q8], b2 = kp[q8];
            acc += a.x * b2.x + a.y * b2.y + a.z * b2.z + a.w * b2.w;
        }
        int zd = n / 49, nr = n - zd * 49, zh = nr / 7, zw = nr - zh * 7;
        int yd = m / 49, mr = m - yd * 49, yh = mr / 7, yw = mr - yh * 7;
        int rpi = (zd - yd + 1) * 169 + (zh - yh + 6) * 13 + (zw - yw + 6);
        acc += table[rpi * 6 + head];
        if (shifted) {
            int d1 = dW * 2 + zd, h1 = hW * 7 + zh, w1 = wW * 7 + zw;
            int d2 = dW * 2 + yd, h2 = hW * 7 + yh, w2 = wW * 7 + yw;
            int c1 = (d1 < 14 ? 0 : (d1 < 15 ? 1 : 2)) * 9
                   + (h1 < 49 ? 0 : (h1 < 53 ? 1 : 2)) * 3
                   + (w1 < 49 ? 0 : (w1 < 53 ? 1 : 2));
            int c2 = (d2 < 14 ? 0 : (d2 < 15 ? 1 : 2)) * 9
                   + (h2 < 49 ? 0 : (h2 < 53 ? 1 : 2)) * 3
                   + (w2 < 49 ? 0 : (w2 < 53 ? 1 : 2));
            if (c1 != c2) acc += 2.0f;
        }
        sc[n * 100 + m] = acc;
    }
    __syncthreads();

    int wwid = tid >> 6, lane = tid & 63;
    for (int n = wwid; n < 98; n += 4) {
        float* row = sc + n * 100;
        float v0 = row[lane];
        float v1 = (lane < 34) ? row[64 + lane] : -3.0e30f;
        float mx = fmaxf(v0, v1);
        #pragma unroll
        for (int off = 32; off; off >>= 1) mx = fmaxf(mx, __shfl_xor(mx, off));
        float e0 = expf(v0 - mx);
        float e1 = (lane < 34) ? expf(v1 - mx) : 0.f;
        float s = e0 + e1;
        #pragma unroll
        for (int off = 32; off; off >>= 1) s += __shfl_xor(s, off);
        float inv = 1.0f / s;
        row[lane] = e0 * inv;
        if (lane < 34) row[64 + lane] = e1 * inv;
    }
    __syncthreads();

    for (int idx = tid; idx < 3136; idx += 256) {
        int n = idx >> 5, dd = idx & 31;
        const float* row = sc + n * 100;
        float acc = 0.f;
        for (int m = 0; m < 98; ++m) acc += row[m] * vs[m * 32 + dd];
        out[(size_t)(r0 + n) * 192 + head * 32 + dd] = f2b(acc);
    }
}

extern "C" void kernel_launch(void* const* d_in, const int* in_sizes, int n_in,
                              void* d_out, int out_size, void* d_ws, size_t ws_size,
                              hipStream_t stream) {
    (void)in_sizes; (void)n_in; (void)out_size;
    const float* x      = (const float*)d_in[0];
    const float* ln1_g  = (const float*)d_in[1];
    const float* ln1_b  = (const float*)d_in[2];
    const float* qkv_w  = (const float*)d_in[3];
    const float* qkv_b  = (const float*)d_in[4];
    const float* proj_w = (const float*)d_in[5];
    const float* proj_b = (const float*)d_in[6];
    const float* table  = (const float*)d_in[7];
    const float* ln2_g  = (const float*)d_in[8];
    const float* ln2_b  = (const float*)d_in[9];
    const float* fc1_w  = (const float*)d_in[10];
    const float* fc1_b  = (const float*)d_in[11];
    const float* fc2_w  = (const float*)d_in[12];
    const float* fc2_b  = (const float*)d_in[13];
    float* out = (float*)d_out;

    // ws layout: bf16 weights | bufA (CR x 192 bf16) | bufQ (CR x 768 bf16)
    const int NQ = 576 * 192, NP = 192 * 192, N1 = 768 * 192, N2 = 192 * 768;
    const size_t WTOT = 2ull * (NQ + NP + N1 + N2);          // 884736 elements
    unsigned short* wq = (unsigned short*)d_ws;
    unsigned short* wp = wq + 2 * NQ;
    unsigned short* w1 = wp + 2 * NP;
    unsigned short* w2 = w1 + 2 * N1;
    unsigned short* bufbase = wq + WTOT;

    const size_t per_win_bytes = 98ull * (192 + 768) * sizeof(unsigned short);
    int wpc = 64;
    const int cands[5] = {1024, 512, 256, 128, 64};
    for (int ci = 0; ci < 5; ++ci) {
        if (WTOT * 2 + (size_t)cands[ci] * per_win_bytes <= ws_size) { wpc = cands[ci]; break; }
    }
    const int NC = 1024 / wpc;
    const int CR = 98 * wpc;                 // multiple of 128 for wpc >= 64
    unsigned short* bufA = bufbase;          // CR x 192
    unsigned short* bufQ = bufA + (size_t)CR * 192;

    // convert weights to bf16 (both layers at once)
    f2b_kernel<<<(2 * NQ + 255) / 256, 256, 0, stream>>>(qkv_w,  wq, 2 * NQ);
    f2b_kernel<<<(2 * NP + 255) / 256, 256, 0, stream>>>(proj_w, wp, 2 * NP);
    f2b_kernel<<<(2 * N1 + 255) / 256, 256, 0, stream>>>(fc1_w,  w1, 2 * N1);
    f2b_kernel<<<(2 * N2 + 255) / 256, 256, 0, stream>>>(fc2_w,  w2, 2 * N2);

    for (int i = 0; i < 2; ++i) {
        const int shifted = (i == 1);
        const float* xsrc = (i == 0) ? x : out;
        for (int c = 0; c < NC; ++c) {
            const int row_off = c * CR;
            const int widx_off = c * wpc;
            ln_kernel<<<CR / 4, 256, 0, stream>>>(
                xsrc, ln1_g + i * 192, ln1_b + i * 192, bufA, shifted ? 2 : 1, row_off);
            gemm_kernel<<<(CR / 128) * 9, 256, 0, stream>>>(
                bufA, wq + (size_t)i * NQ, qkv_b + i * 576,
                bufQ, nullptr, 576, 192, 0, 0, 0);
            attn_kernel<<<dim3(wpc, 6), 256, 0, stream>>>(
                bufQ, table + i * 3042, bufA, shifted, widx_off);
            gemm_kernel<<<(CR / 128) * 3, 256, 0, stream>>>(
                bufA, wp + (size_t)i * NP, proj_b + i * 192,
                out, xsrc, 192, 192, 2, shifted, row_off);
        }
        for (int c = 0; c < NC; ++c) {
            const int row_off = c * CR;
            ln_kernel<<<CR / 4, 256, 0, stream>>>(
                out, ln2_g + i * 192, ln2_b + i * 192, bufA, 0, row_off);
            gemm_kernel<<<(CR / 128) * 12, 256, 0, stream>>>(
                bufA, w1 + (size_t)i * N1, fc1_b + i * 768,
                bufQ, nullptr, 768, 192, 1, 0, 0);
            gemm_kernel<<<(CR / 128) * 3, 256, 0, stream>>>(
                bufQ, w2 + (size_t)i * N2, fc2_b + i * 192,
                out + (size_t)row_off * 192, out + (size_t)row_off * 192,
                192, 768, 3, 0, 0);
        }
    }
}

// Round 4
// 1577.244 us; speedup vs baseline: 2.6882x; 1.1122x over previous
//
#include <hip/hip_runtime.h>
#include <math.h>

#define T_TOKENS 100352

typedef short s16x8 __attribute__((ext_vector_type(8)));
typedef float f32x4 __attribute__((ext_vector_type(4)));

__device__ __forceinline__ unsigned short f2b(float f) {
    union { float f; unsigned u; } x; x.f = f;
    unsigned r = x.u + 0x7fffu + ((x.u >> 16) & 1u);   // RNE
    return (unsigned short)(r >> 16);
}
__device__ __forceinline__ float b2f(unsigned short h) {
    union { unsigned u; float f; } x; x.u = (unsigned)h << 16;
    return x.f;
}

#define GLOAD_LDS16(gsrc, ldst) __builtin_amdgcn_global_load_lds( \
    (const __attribute__((address_space(1))) void*)(gsrc), \
    (__attribute__((address_space(3))) void*)(ldst), 16, 0, 0)

// Map window-layout row r (widx*98 + n) to flat token index. Self-inverse
// pairing: gather (LN) and scatter (proj) use the same mapping.
__device__ __forceinline__ int win_row_to_token(int r, int shifted) {
    int widx = r / 98;
    int n = r - widx * 98;
    int b = widx >> 9;
    int remw = widx & 511;
    int dW = remw >> 6, hW = (remw >> 3) & 7, wW = remw & 7;
    int zd = n / 49;
    int nr = n - zd * 49;
    int zh = nr / 7, zw = nr - zh * 7;
    int d = dW * 2 + zd, h = hW * 7 + zh, w = wW * 7 + zw;
    if (shifted) {
        d = (d + 1) & 15;
        h += 3; if (h >= 56) h -= 56;
        w += 3; if (w >= 56) w -= 56;
    }
    return ((b * 16 + d) * 56 + h) * 56 + w;
}

__global__ __launch_bounds__(256) void f2b_kernel(
    const float* __restrict__ in, unsigned short* __restrict__ out, int n)
{
    int i = blockIdx.x * 256 + threadIdx.x;
    if (i < n) out[i] = f2b(in[i]);
}

// Precompute relative-position bias: bm[l][h][n][m] = table[l][rpi(n,m)][h].
// total = 2 * 6 * 98 * 98 = 115248
__global__ __launch_bounds__(256) void bias_kernel(
    const float* __restrict__ table, float* __restrict__ bm)
{
    int idx = blockIdx.x * 256 + threadIdx.x;
    if (idx >= 115248) return;
    int l = idx / 57624;
    int r = idx - l * 57624;
    int h = r / 9604;
    int e = r - h * 9604;
    int n = e / 98, m = e - n * 98;
    int zd = n / 49, nr = n - zd * 49, zh = nr / 7, zw = nr - zh * 7;
    int yd = m / 49, mr = m - yd * 49, yh = mr / 7, yw = mr - yh * 7;
    int rpi = (zd - yd + 1) * 169 + (zh - yh + 6) * 13 + (zw - yw + 6);
    bm[idx] = table[l * 3042 + rpi * 6 + h];
}

// LayerNorm over C=192 -> bf16 out. mode 0: linear; 1: window gather; 2: shifted gather.
__global__ __launch_bounds__(256) void ln_kernel(
    const float* __restrict__ x, const float* __restrict__ g,
    const float* __restrict__ b, unsigned short* __restrict__ out, int mode, int row_off)
{
    int r = blockIdx.x * 4 + (threadIdx.x >> 6);
    int lane = threadIdx.x & 63;
    int t = (mode == 0) ? (row_off + r) : win_row_to_token(row_off + r, mode == 2);
    const float* xp = x + (size_t)t * 192;
    float v0 = xp[lane], v1 = xp[lane + 64], v2 = xp[lane + 128];
    float s = v0 + v1 + v2;
    float sq = v0 * v0 + v1 * v1 + v2 * v2;
    #pragma unroll
    for (int off = 32; off; off >>= 1) {
        s += __shfl_xor(s, off);
        sq += __shfl_xor(sq, off);
    }
    float mu = s * (1.0f / 192.0f);
    float var = sq * (1.0f / 192.0f) - mu * mu;
    float rs = rsqrtf(var + 1e-5f);
    unsigned short* op = out + (size_t)r * 192;
    op[lane]       = f2b((v0 - mu) * rs * g[lane]       + b[lane]);
    op[lane + 64]  = f2b((v1 - mu) * rs * g[lane + 64]  + b[lane + 64]);
    op[lane + 128] = f2b((v2 - mu) * rs * g[lane + 128] + b[lane + 128]);
}

// bf16 MFMA GEMM: out[M,N] = A[M,K] @ Wb[N,K]^T + bias. (unchanged from R3)
__global__ __launch_bounds__(256) void gemm_kernel(
    const unsigned short* __restrict__ A, const unsigned short* __restrict__ Wb,
    const float* __restrict__ bias, void* outp, const float* resx,
    int N, int K, int ep, int shifted, int row_off)
{
    __shared__ short As[128 * 64];
    __shared__ short Bs[64 * 64];
    const int ntiles = N >> 6;
    const int bm = blockIdx.x / ntiles;
    const int bn = blockIdx.x - bm * ntiles;
    const int r0 = bm << 7, n0 = bn << 6;
    const int tid = threadIdx.x;
    const int wid = tid >> 6, lane = tid & 63;
    const int wrow = (wid >> 1) << 6;
    const int wcol = (wid & 1) << 5;
    const int srow = lane >> 3;
    const int sslot = lane & 7;

    f32x4 acc[4][2];
    #pragma unroll
    for (int mi = 0; mi < 4; ++mi)
        #pragma unroll
        for (int ni = 0; ni < 2; ++ni)
            acc[mi][ni] = (f32x4){0.f, 0.f, 0.f, 0.f};

    for (int k0 = 0; k0 < K; k0 += 64) {
        #pragma unroll
        for (int g = 0; g < 4; ++g) {
            int row = wid * 32 + g * 8 + srow;
            const unsigned short* src =
                A + (size_t)(r0 + row) * K + k0 + ((sslot ^ (row & 7)) << 3);
            GLOAD_LDS16(src, &As[(wid * 32 + g * 8) * 64]);
        }
        #pragma unroll
        for (int g = 0; g < 2; ++g) {
            int row = wid * 16 + g * 8 + srow;
            const unsigned short* src =
                Wb + (size_t)(n0 + row) * K + k0 + ((sslot ^ (row & 7)) << 3);
            GLOAD_LDS16(src, &Bs[(wid * 16 + g * 8) * 64]);
        }
        __syncthreads();
        #pragma unroll
        for (int ks = 0; ks < 2; ++ks) {
            const int q = ks * 4 + (lane >> 4);
            s16x8 bfr[2];
            #pragma unroll
            for (int ni = 0; ni < 2; ++ni) {
                int col = wcol + ni * 16 + (lane & 15);
                bfr[ni] = *(const s16x8*)&Bs[col * 64 + ((q ^ (col & 7)) << 3)];
            }
            #pragma unroll
            for (int mi = 0; mi < 4; ++mi) {
                int row = wrow + mi * 16 + (lane & 15);
                s16x8 afr = *(const s16x8*)&As[row * 64 + ((q ^ (row & 7)) << 3)];
                #pragma unroll
                for (int ni = 0; ni < 2; ++ni)
                    acc[mi][ni] = __builtin_amdgcn_mfma_f32_16x16x32_bf16(
                        afr, bfr[ni], acc[mi][ni], 0, 0, 0);
            }
        }
        __syncthreads();
    }

    #pragma unroll
    for (int mi = 0; mi < 4; ++mi) {
        #pragma unroll
        for (int ni = 0; ni < 2; ++ni) {
            int colg = n0 + wcol + ni * 16 + (lane & 15);
            float bv = bias[colg];
            #pragma unroll
            for (int rg = 0; rg < 4; ++rg) {
                int rowl = r0 + wrow + mi * 16 + ((lane >> 4) << 2) + rg;
                float v = acc[mi][ni][rg] + bv;
                if (ep == 0) {
                    ((unsigned short*)outp)[(size_t)rowl * N + colg] = f2b(v);
                } else if (ep == 1) {
                    v = 0.5f * v * (1.0f + erff(v * 0.70710678118654752f));
                    ((unsigned short*)outp)[(size_t)rowl * N + colg] = f2b(v);
                } else {
                    int t = (ep == 2) ? win_row_to_token(row_off + rowl, shifted) : rowl;
                    size_t o = (size_t)t * 192 + colg;
                    ((float*)outp)[o] = resx[o] + v;
                }
            }
        }
    }
}

// MFMA attention. One block per (local window, head); 4 waves.
// N=98 padded to 112 (M/N tiles), K(kv) padded to 128 for PV.
// S kept f32 in LDS; softmax rewrites it in place as bf16 P (pad cols zeroed).
__global__ __launch_bounds__(256) void attn_kernel(
    const unsigned short* __restrict__ qkv, const float* __restrict__ bm,
    unsigned short* __restrict__ out, int shifted, int widx_off)
{
    __shared__ __align__(16) short Qs[112 * 40];
    __shared__ __align__(16) short Ks[112 * 40];
    __shared__ __align__(16) short Vt[32 * 136];
    __shared__ __align__(16) float Ss[112 * 116];
    __shared__ int rid[112];

    const int wloc = blockIdx.x;
    const int head = blockIdx.y;
    const int tid = threadIdx.x;
    const int wid = tid >> 6, lane = tid & 63;
    const int r0 = wloc * 98;
    const float scale = 0.17677669529663687f;   // 32^-0.5

    const int remw = (widx_off + wloc) & 511;
    const int dW = remw >> 6, hW = (remw >> 3) & 7, wW = remw & 7;

    // region ids (for shift mask)
    if (tid < 112) {
        int r = 0;
        if (tid < 98) {
            int zd = tid / 49, nr = tid - zd * 49, zh = nr / 7, zw = nr - zh * 7;
            int d1 = dW * 2 + zd, h1 = hW * 7 + zh, w1 = wW * 7 + zw;
            r = (d1 < 14 ? 0 : (d1 < 15 ? 1 : 2)) * 9
              + (h1 < 49 ? 0 : (h1 < 53 ? 1 : 2)) * 3
              + (w1 < 49 ? 0 : (w1 < 53 ? 1 : 2));
        }
        rid[tid] = r;
    }

    // stage Q,K row-major [112][40]; V transposed [32][136]
    for (int idx = tid; idx < 1568; idx += 256) {      // 98 rows x 16 uints
        int n = idx >> 4, dp = idx & 15;
        size_t base = (size_t)(r0 + n) * 576 + head * 32 + dp * 2;
        unsigned qv = *(const unsigned*)&qkv[base];
        unsigned kv = *(const unsigned*)&qkv[base + 192];
        unsigned vv = *(const unsigned*)&qkv[base + 384];
        ((unsigned*)Qs)[n * 20 + dp] = qv;
        ((unsigned*)Ks)[n * 20 + dp] = kv;
        ((unsigned short*)Vt)[(2 * dp) * 136 + n]     = (unsigned short)(vv & 0xffff);
        ((unsigned short*)Vt)[(2 * dp + 1) * 136 + n] = (unsigned short)(vv >> 16);
    }
    // zero V pad rows kv=98..127 (P pad cols are 0; avoid 0*NaN)
    for (int idx = tid; idx < 960; idx += 256) {
        int dd = idx / 30, kvp = 98 + idx - (idx / 30) * 30;
        ((unsigned short*)Vt)[dd * 136 + kvp] = 0;
    }
    __syncthreads();

    // QK^T: waves split 7 m-tiles; fuse scale+bias+mask into S write
    for (int mt = wid; mt < 7; mt += 4) {
        s16x8 qa = *(const s16x8*)&Qs[(mt * 16 + (lane & 15)) * 40 + ((lane >> 4) << 3)];
        #pragma unroll
        for (int nt = 0; nt < 7; ++nt) {
            s16x8 kb = *(const s16x8*)&Ks[(nt * 16 + (lane & 15)) * 40 + ((lane >> 4) << 3)];
            f32x4 s = __builtin_amdgcn_mfma_f32_16x16x32_bf16(
                qa, kb, (f32x4){0.f, 0.f, 0.f, 0.f}, 0, 0, 0);
            int kv = nt * 16 + (lane & 15);
            #pragma unroll
            for (int rg = 0; rg < 4; ++rg) {
                int q = mt * 16 + ((lane >> 4) << 2) + rg;
                if (q < 98 && kv < 98) {
                    float val = s[rg] * scale + bm[(head * 98 + q) * 98 + kv];
                    if (shifted && rid[q] != rid[kv]) val += 2.0f;
                    Ss[q * 116 + kv] = val;
                }
            }
        }
    }
    __syncthreads();

    // softmax per row; write P bf16 in place, zero pad cols 98..127
    for (int n = wid; n < 98; n += 4) {
        float* row = Ss + n * 116;
        float v0 = row[lane];
        float v1 = (lane < 34) ? row[64 + lane] : -3.0e30f;
        float mx = fmaxf(v0, v1);
        #pragma unroll
        for (int off = 32; off; off >>= 1) mx = fmaxf(mx, __shfl_xor(mx, off));
        float e0 = expf(v0 - mx);
        float e1 = (lane < 34) ? expf(v1 - mx) : 0.f;
        float s = e0 + e1;
        #pragma unroll
        for (int off = 32; off; off >>= 1) s += __shfl_xor(s, off);
        float inv = 1.0f / s;
        unsigned short* prow = (unsigned short*)row;
        prow[lane] = f2b(e0 * inv);
        prow[64 + lane] = (lane < 34) ? f2b(e1 * inv) : (unsigned short)0;
    }
    __syncthreads();

    // PV: O[q][dd] = sum_kv P[q][kv] * V[kv][dd]
    for (int mt = wid; mt < 7; mt += 4) {
        f32x4 o0 = {0.f, 0.f, 0.f, 0.f}, o1 = {0.f, 0.f, 0.f, 0.f};
        const unsigned short* prow =
            (const unsigned short*)(Ss + (mt * 16 + (lane & 15)) * 116);
        #pragma unroll
        for (int ks = 0; ks < 4; ++ks) {
            s16x8 pa = *(const s16x8*)&prow[ks * 32 + ((lane >> 4) << 3)];
            s16x8 vb0 = *(const s16x8*)&((const short*)Vt)[
                (lane & 15) * 136 + ks * 32 + ((lane >> 4) << 3)];
            s16x8 vb1 = *(const s16x8*)&((const short*)Vt)[
                (16 + (lane & 15)) * 136 + ks * 32 + ((lane >> 4) << 3)];
            o0 = __builtin_amdgcn_mfma_f32_16x16x32_bf16(pa, vb0, o0, 0, 0, 0);
            o1 = __builtin_amdgcn_mfma_f32_16x16x32_bf16(pa, vb1, o1, 0, 0, 0);
        }
        #pragma unroll
        for (int rg = 0; rg < 4; ++rg) {
            int q = mt * 16 + ((lane >> 4) << 2) + rg;
            if (q < 98) {
                size_t ob = (size_t)(r0 + q) * 192 + head * 32;
                out[ob + (lane & 15)]      = f2b(o0[rg]);
                out[ob + 16 + (lane & 15)] = f2b(o1[rg]);
            }
        }
    }
}

extern "C" void kernel_launch(void* const* d_in, const int* in_sizes, int n_in,
                              void* d_out, int out_size, void* d_ws, size_t ws_size,
                              hipStream_t stream) {
    (void)in_sizes; (void)n_in; (void)out_size;
    const float* x      = (const float*)d_in[0];
    const float* ln1_g  = (const float*)d_in[1];
    const float* ln1_b  = (const float*)d_in[2];
    const float* qkv_w  = (const float*)d_in[3];
    const float* qkv_b  = (const float*)d_in[4];
    const float* proj_w = (const float*)d_in[5];
    const float* proj_b = (const float*)d_in[6];
    const float* table  = (const float*)d_in[7];
    const float* ln2_g  = (const float*)d_in[8];
    const float* ln2_b  = (const float*)d_in[9];
    const float* fc1_w  = (const float*)d_in[10];
    const float* fc1_b  = (const float*)d_in[11];
    const float* fc2_w  = (const float*)d_in[12];
    const float* fc2_b  = (const float*)d_in[13];
    float* out = (float*)d_out;

    // ws layout: bf16 weights | biasmap f32 | bufA bf16 | bufQ bf16
    const int NQ = 576 * 192, NP = 192 * 192, N1 = 768 * 192, N2 = 192 * 768;
    const size_t WTOT = 2ull * (NQ + NP + N1 + N2);
    unsigned short* wq = (unsigned short*)d_ws;
    unsigned short* wp = wq + 2 * NQ;
    unsigned short* w1 = wp + 2 * NP;
    unsigned short* w2 = w1 + 2 * N1;
    float* bmap = (float*)(wq + WTOT);
    unsigned short* bufbase = (unsigned short*)(bmap + 115248);
    const size_t fixed_bytes = WTOT * 2 + 115248 * 4;

    const size_t per_win_bytes = 98ull * (192 + 768) * sizeof(unsigned short);
    int wpc = 64;
    const int cands[5] = {1024, 512, 256, 128, 64};
    for (int ci = 0; ci < 5; ++ci) {
        if (fixed_bytes + (size_t)cands[ci] * per_win_bytes <= ws_size) { wpc = cands[ci]; break; }
    }
    const int NC = 1024 / wpc;
    const int CR = 98 * wpc;
    unsigned short* bufA = bufbase;
    unsigned short* bufQ = bufA + (size_t)CR * 192;

    f2b_kernel<<<(2 * NQ + 255) / 256, 256, 0, stream>>>(qkv_w,  wq, 2 * NQ);
    f2b_kernel<<<(2 * NP + 255) / 256, 256, 0, stream>>>(proj_w, wp, 2 * NP);
    f2b_kernel<<<(2 * N1 + 255) / 256, 256, 0, stream>>>(fc1_w,  w1, 2 * N1);
    f2b_kernel<<<(2 * N2 + 255) / 256, 256, 0, stream>>>(fc2_w,  w2, 2 * N2);
    bias_kernel<<<(115248 + 255) / 256, 256, 0, stream>>>(table, bmap);

    for (int i = 0; i < 2; ++i) {
        const int shifted = (i == 1);
        const float* xsrc = (i == 0) ? x : out;
        for (int c = 0; c < NC; ++c) {
            const int row_off = c * CR;
            const int widx_off = c * wpc;
            ln_kernel<<<CR / 4, 256, 0, stream>>>(
                xsrc, ln1_g + i * 192, ln1_b + i * 192, bufA, shifted ? 2 : 1, row_off);
            gemm_kernel<<<(CR / 128) * 9, 256, 0, stream>>>(
                bufA, wq + (size_t)i * NQ, qkv_b + i * 576,
                bufQ, nullptr, 576, 192, 0, 0, 0);
            attn_kernel<<<dim3(wpc, 6), 256, 0, stream>>>(
                bufQ, bmap + (size_t)i * 57624, bufA, shifted, widx_off);
            gemm_kernel<<<(CR / 128) * 3, 256, 0, stream>>>(
                bufA, wp + (size_t)i * NP, proj_b + i * 192,
                out, xsrc, 192, 192, 2, shifted, row_off);
        }
        for (int c = 0; c < NC; ++c) {
            const int row_off = c * CR;
            ln_kernel<<<CR / 4, 256, 0, stream>>>(
                out, ln2_g + i * 192, ln2_b + i * 192, bufA, 0, row_off);
            gemm_kernel<<<(CR / 128) * 12, 256, 0, stream>>>(
                bufA, w1 + (size_t)i * N1, fc1_b + i * 768,
                bufQ, nullptr, 768, 192, 1, 0, 0);
            gemm_kernel<<<(CR / 128) * 3, 256, 0, stream>>>(
                bufQ, w2 + (size_t)i * N2, fc2_b + i * 192,
                out + (size_t)row_off * 192, out + (size_t)row_off * 192,
                192, 768, 3, 0, 0);
        }
    }
}

// Round 5
// 1181.875 us; speedup vs baseline: 3.5874x; 1.3345x over previous
//
#include <hip/hip_runtime.h>
#include <math.h>

#define T_TOKENS 100352

typedef short s16x8 __attribute__((ext_vector_type(8)));
typedef float f32x4 __attribute__((ext_vector_type(4)));

__device__ __forceinline__ unsigned short f2b(float f) {
    union { float f; unsigned u; } x; x.f = f;
    unsigned r = x.u + 0x7fffu + ((x.u >> 16) & 1u);   // RNE
    return (unsigned short)(r >> 16);
}
__device__ __forceinline__ float b2f(unsigned short h) {
    union { unsigned u; float f; } x; x.u = (unsigned)h << 16;
    return x.f;
}

#define GLOAD_LDS16(gsrc, ldst) __builtin_amdgcn_global_load_lds( \
    (const __attribute__((address_space(1))) void*)(gsrc), \
    (__attribute__((address_space(3))) void*)(ldst), 16, 0, 0)

// Map window-layout row r (widx*98 + n) to flat token index. Self-inverse
// pairing: gather (LN) and scatter (proj) use the same mapping.
__device__ __forceinline__ int win_row_to_token(int r, int shifted) {
    int widx = r / 98;
    int n = r - widx * 98;
    int b = widx >> 9;
    int remw = widx & 511;
    int dW = remw >> 6, hW = (remw >> 3) & 7, wW = remw & 7;
    int zd = n / 49;
    int nr = n - zd * 49;
    int zh = nr / 7, zw = nr - zh * 7;
    int d = dW * 2 + zd, h = hW * 7 + zh, w = wW * 7 + zw;
    if (shifted) {
        d = (d + 1) & 15;
        h += 3; if (h >= 56) h -= 56;
        w += 3; if (w >= 56) w -= 56;
    }
    return ((b * 16 + d) * 56 + h) * 56 + w;
}

__global__ __launch_bounds__(256) void f2b_kernel(
    const float* __restrict__ in, unsigned short* __restrict__ out, int n)
{
    int i = blockIdx.x * 256 + threadIdx.x;
    if (i < n) out[i] = f2b(in[i]);
}

// Precompute relative-position bias: bm[l][h][n][m] = table[l][rpi(n,m)][h].
__global__ __launch_bounds__(256) void bias_kernel(
    const float* __restrict__ table, float* __restrict__ bm)
{
    int idx = blockIdx.x * 256 + threadIdx.x;
    if (idx >= 115248) return;
    int l = idx / 57624;
    int r = idx - l * 57624;
    int h = r / 9604;
    int e = r - h * 9604;
    int n = e / 98, m = e - n * 98;
    int zd = n / 49, nr = n - zd * 49, zh = nr / 7, zw = nr - zh * 7;
    int yd = m / 49, mr = m - yd * 49, yh = mr / 7, yw = mr - yh * 7;
    int rpi = (zd - yd + 1) * 169 + (zh - yh + 6) * 13 + (zw - yw + 6);
    bm[idx] = table[l * 3042 + rpi * 6 + h];
}

// LayerNorm over C=192 -> bf16 out. mode 0: linear; 1: window gather; 2: shifted gather.
__global__ __launch_bounds__(256) void ln_kernel(
    const float* __restrict__ x, const float* __restrict__ g,
    const float* __restrict__ b, unsigned short* __restrict__ out, int mode, int row_off)
{
    int r = blockIdx.x * 4 + (threadIdx.x >> 6);
    int lane = threadIdx.x & 63;
    int t = (mode == 0) ? (row_off + r) : win_row_to_token(row_off + r, mode == 2);
    const float* xp = x + (size_t)t * 192;
    float v0 = xp[lane], v1 = xp[lane + 64], v2 = xp[lane + 128];
    float s = v0 + v1 + v2;
    float sq = v0 * v0 + v1 * v1 + v2 * v2;
    #pragma unroll
    for (int off = 32; off; off >>= 1) {
        s += __shfl_xor(s, off);
        sq += __shfl_xor(sq, off);
    }
    float mu = s * (1.0f / 192.0f);
    float var = sq * (1.0f / 192.0f) - mu * mu;
    float rs = rsqrtf(var + 1e-5f);
    unsigned short* op = out + (size_t)r * 192;
    op[lane]       = f2b((v0 - mu) * rs * g[lane]       + b[lane]);
    op[lane + 64]  = f2b((v1 - mu) * rs * g[lane + 64]  + b[lane + 64]);
    op[lane + 128] = f2b((v2 - mu) * rs * g[lane + 128] + b[lane + 128]);
}

// bf16 MFMA GEMM: out[M,N] = A[M,K] @ Wb[N,K]^T + bias. (unchanged from R4)
__global__ __launch_bounds__(256) void gemm_kernel(
    const unsigned short* __restrict__ A, const unsigned short* __restrict__ Wb,
    const float* __restrict__ bias, void* outp, const float* resx,
    int N, int K, int ep, int shifted, int row_off)
{
    __shared__ short As[128 * 64];
    __shared__ short Bs[64 * 64];
    const int ntiles = N >> 6;
    const int bm = blockIdx.x / ntiles;
    const int bn = blockIdx.x - bm * ntiles;
    const int r0 = bm << 7, n0 = bn << 6;
    const int tid = threadIdx.x;
    const int wid = tid >> 6, lane = tid & 63;
    const int wrow = (wid >> 1) << 6;
    const int wcol = (wid & 1) << 5;
    const int srow = lane >> 3;
    const int sslot = lane & 7;

    f32x4 acc[4][2];
    #pragma unroll
    for (int mi = 0; mi < 4; ++mi)
        #pragma unroll
        for (int ni = 0; ni < 2; ++ni)
            acc[mi][ni] = (f32x4){0.f, 0.f, 0.f, 0.f};

    for (int k0 = 0; k0 < K; k0 += 64) {
        #pragma unroll
        for (int g = 0; g < 4; ++g) {
            int row = wid * 32 + g * 8 + srow;
            const unsigned short* src =
                A + (size_t)(r0 + row) * K + k0 + ((sslot ^ (row & 7)) << 3);
            GLOAD_LDS16(src, &As[(wid * 32 + g * 8) * 64]);
        }
        #pragma unroll
        for (int g = 0; g < 2; ++g) {
            int row = wid * 16 + g * 8 + srow;
            const unsigned short* src =
                Wb + (size_t)(n0 + row) * K + k0 + ((sslot ^ (row & 7)) << 3);
            GLOAD_LDS16(src, &Bs[(wid * 16 + g * 8) * 64]);
        }
        __syncthreads();
        #pragma unroll
        for (int ks = 0; ks < 2; ++ks) {
            const int q = ks * 4 + (lane >> 4);
            s16x8 bfr[2];
            #pragma unroll
            for (int ni = 0; ni < 2; ++ni) {
                int col = wcol + ni * 16 + (lane & 15);
                bfr[ni] = *(const s16x8*)&Bs[col * 64 + ((q ^ (col & 7)) << 3)];
            }
            #pragma unroll
            for (int mi = 0; mi < 4; ++mi) {
                int row = wrow + mi * 16 + (lane & 15);
                s16x8 afr = *(const s16x8*)&As[row * 64 + ((q ^ (row & 7)) << 3)];
                #pragma unroll
                for (int ni = 0; ni < 2; ++ni)
                    acc[mi][ni] = __builtin_amdgcn_mfma_f32_16x16x32_bf16(
                        afr, bfr[ni], acc[mi][ni], 0, 0, 0);
            }
        }
        __syncthreads();
    }

    #pragma unroll
    for (int mi = 0; mi < 4; ++mi) {
        #pragma unroll
        for (int ni = 0; ni < 2; ++ni) {
            int colg = n0 + wcol + ni * 16 + (lane & 15);
            float bv = bias[colg];
            #pragma unroll
            for (int rg = 0; rg < 4; ++rg) {
                int rowl = r0 + wrow + mi * 16 + ((lane >> 4) << 2) + rg;
                float v = acc[mi][ni][rg] + bv;
                if (ep == 0) {
                    ((unsigned short*)outp)[(size_t)rowl * N + colg] = f2b(v);
                } else if (ep == 1) {
                    v = 0.5f * v * (1.0f + erff(v * 0.70710678118654752f));
                    ((unsigned short*)outp)[(size_t)rowl * N + colg] = f2b(v);
                } else {
                    int t = (ep == 2) ? win_row_to_token(row_off + rowl, shifted) : rowl;
                    size_t o = (size_t)t * 192 + colg;
                    ((float*)outp)[o] = resx[o] + v;
                }
            }
        }
    }
}

// MFMA attention, in-register softmax. One block per (window, head); 4 waves.
// LDS: union buffer (phase1: Q,K row-major [112][40]; phase2: P bf16 [112][136])
//      + Vt [32][136] + rid. Total ~38.7 KB -> 4 blocks/CU.
__global__ __launch_bounds__(256, 4) void attn_kernel(
    const unsigned short* __restrict__ qkv, const float* __restrict__ bm,
    unsigned short* __restrict__ out, int shifted, int widx_off)
{
    __shared__ __align__(16) short QKP[112 * 136];
    __shared__ __align__(16) short Vt[32 * 136];
    __shared__ int rid[112];

    const int wloc = blockIdx.x;
    const int head = blockIdx.y;
    const int tid = threadIdx.x;
    const int wid = tid >> 6, lane = tid & 63;
    const int r0 = wloc * 98;
    const float scale = 0.17677669529663687f;   // 32^-0.5

    short* Qs = QKP;
    short* Ks = QKP + 112 * 40;

    const int remw = (widx_off + wloc) & 511;
    const int dW = remw >> 6, hW = (remw >> 3) & 7, wW = remw & 7;

    if (tid < 112) {
        int r = 0;
        if (tid < 98) {
            int zd = tid / 49, nr = tid - zd * 49, zh = nr / 7, zw = nr - zh * 7;
            int d1 = dW * 2 + zd, h1 = hW * 7 + zh, w1 = wW * 7 + zw;
            r = (d1 < 14 ? 0 : (d1 < 15 ? 1 : 2)) * 9
              + (h1 < 49 ? 0 : (h1 < 53 ? 1 : 2)) * 3
              + (w1 < 49 ? 0 : (w1 < 53 ? 1 : 2));
        }
        rid[tid] = r;
    }

    // stage Q,K row-major [112][40]; V transposed [32][136]
    for (int idx = tid; idx < 1568; idx += 256) {
        int n = idx >> 4, dp = idx & 15;
        size_t base = (size_t)(r0 + n) * 576 + head * 32 + dp * 2;
        unsigned qv = *(const unsigned*)&qkv[base];
        unsigned kv = *(const unsigned*)&qkv[base + 192];
        unsigned vv = *(const unsigned*)&qkv[base + 384];
        ((unsigned*)Qs)[n * 20 + dp] = qv;
        ((unsigned*)Ks)[n * 20 + dp] = kv;
        ((unsigned short*)Vt)[(2 * dp) * 136 + n]     = (unsigned short)(vv & 0xffff);
        ((unsigned short*)Vt)[(2 * dp + 1) * 136 + n] = (unsigned short)(vv >> 16);
    }
    // zero V pad rows kv=98..127 (avoid 0*NaN in PV)
    for (int idx = tid; idx < 960; idx += 256) {
        int dd = idx / 30, kvp = 98 + (idx - (idx / 30) * 30);
        ((unsigned short*)Vt)[dd * 136 + kvp] = 0;
    }
    __syncthreads();

    // QK^T + bias + mask + in-register softmax; keep P packed bf16 in regs.
    unsigned pk[2][7][2];
    #pragma unroll
    for (int t = 0; t < 2; ++t) {
        int mt = wid + 4 * t;
        if (mt < 7) {
            s16x8 qa = *(const s16x8*)&Qs[(mt * 16 + (lane & 15)) * 40 + ((lane >> 4) << 3)];
            f32x4 sacc[7];
            #pragma unroll
            for (int nt = 0; nt < 7; ++nt) {
                s16x8 kb = *(const s16x8*)&Ks[(nt * 16 + (lane & 15)) * 40 + ((lane >> 4) << 3)];
                sacc[nt] = __builtin_amdgcn_mfma_f32_16x16x32_bf16(
                    qa, kb, (f32x4){0.f, 0.f, 0.f, 0.f}, 0, 0, 0);
            }
            const int kvc = lane & 15;
            #pragma unroll
            for (int nt = 0; nt < 7; ++nt) {
                int kv = nt * 16 + kvc;
                #pragma unroll
                for (int rg = 0; rg < 4; ++rg) {
                    int q = mt * 16 + ((lane >> 4) << 2) + rg;
                    float val = -1e30f;
                    if (q < 98 && kv < 98) {
                        val = sacc[nt][rg] * scale + bm[(head * 98 + q) * 98 + kv];
                        if (shifted && rid[q] != rid[kv]) val += 2.0f;
                    }
                    sacc[nt][rg] = val;
                }
            }
            #pragma unroll
            for (int rg = 0; rg < 4; ++rg) {
                float mx = sacc[0][rg];
                #pragma unroll
                for (int nt = 1; nt < 7; ++nt) mx = fmaxf(mx, sacc[nt][rg]);
                #pragma unroll
                for (int off = 1; off < 16; off <<= 1) mx = fmaxf(mx, __shfl_xor(mx, off));
                float sum = 0.f;
                #pragma unroll
                for (int nt = 0; nt < 7; ++nt) {
                    float e = expf(sacc[nt][rg] - mx);
                    sacc[nt][rg] = e;
                    sum += e;
                }
                #pragma unroll
                for (int off = 1; off < 16; off <<= 1) sum += __shfl_xor(sum, off);
                float inv = 1.0f / sum;
                #pragma unroll
                for (int nt = 0; nt < 7; ++nt) sacc[nt][rg] *= inv;
            }
            #pragma unroll
            for (int nt = 0; nt < 7; ++nt) {
                pk[t][nt][0] = (unsigned)f2b(sacc[nt][0]) | ((unsigned)f2b(sacc[nt][1]) << 16);
                pk[t][nt][1] = (unsigned)f2b(sacc[nt][2]) | ((unsigned)f2b(sacc[nt][3]) << 16);
            }
        }
    }
    __syncthreads();   // all Q/K reads complete; safe to overwrite with P

    unsigned short* P = (unsigned short*)QKP;
    #pragma unroll
    for (int t = 0; t < 2; ++t) {
        int mt = wid + 4 * t;
        if (mt < 7) {
            int qb = mt * 16 + ((lane >> 4) << 2);
            #pragma unroll
            for (int nt = 0; nt < 7; ++nt) {
                P[(qb + 0) * 136 + nt * 16 + (lane & 15)] = (unsigned short)(pk[t][nt][0] & 0xffff);
                P[(qb + 1) * 136 + nt * 16 + (lane & 15)] = (unsigned short)(pk[t][nt][0] >> 16);
                P[(qb + 2) * 136 + nt * 16 + (lane & 15)] = (unsigned short)(pk[t][nt][1] & 0xffff);
                P[(qb + 3) * 136 + nt * 16 + (lane & 15)] = (unsigned short)(pk[t][nt][1] >> 16);
            }
            #pragma unroll
            for (int rg = 0; rg < 4; ++rg)
                P[(qb + rg) * 136 + 112 + (lane & 15)] = 0;
        }
    }
    __syncthreads();

    // PV: O[q][dd] = sum_kv P[q][kv] * V[kv][dd]
    #pragma unroll
    for (int t = 0; t < 2; ++t) {
        int mt = wid + 4 * t;
        if (mt < 7) {
            f32x4 o0 = {0.f, 0.f, 0.f, 0.f}, o1 = {0.f, 0.f, 0.f, 0.f};
            const short* prow = (const short*)&P[(mt * 16 + (lane & 15)) * 136 + ((lane >> 4) << 3)];
            #pragma unroll
            for (int ks = 0; ks < 4; ++ks) {
                s16x8 pa = *(const s16x8*)&prow[ks * 32];
                s16x8 vb0 = *(const s16x8*)&Vt[(lane & 15) * 136 + ks * 32 + ((lane >> 4) << 3)];
                s16x8 vb1 = *(const s16x8*)&Vt[((lane & 15) + 16) * 136 + ks * 32 + ((lane >> 4) << 3)];
                o0 = __builtin_amdgcn_mfma_f32_16x16x32_bf16(pa, vb0, o0, 0, 0, 0);
                o1 = __builtin_amdgcn_mfma_f32_16x16x32_bf16(pa, vb1, o1, 0, 0, 0);
            }
            #pragma unroll
            for (int rg = 0; rg < 4; ++rg) {
                int q = mt * 16 + ((lane >> 4) << 2) + rg;
                if (q < 98) {
                    size_t ob = (size_t)(r0 + q) * 192 + head * 32;
                    out[ob + (lane & 15)]      = f2b(o0[rg]);
                    out[ob + 16 + (lane & 15)] = f2b(o1[rg]);
                }
            }
        }
    }
}

extern "C" void kernel_launch(void* const* d_in, const int* in_sizes, int n_in,
                              void* d_out, int out_size, void* d_ws, size_t ws_size,
                              hipStream_t stream) {
    (void)in_sizes; (void)n_in; (void)out_size;
    const float* x      = (const float*)d_in[0];
    const float* ln1_g  = (const float*)d_in[1];
    const float* ln1_b  = (const float*)d_in[2];
    const float* qkv_w  = (const float*)d_in[3];
    const float* qkv_b  = (const float*)d_in[4];
    const float* proj_w = (const float*)d_in[5];
    const float* proj_b = (const float*)d_in[6];
    const float* table  = (const float*)d_in[7];
    const float* ln2_g  = (const float*)d_in[8];
    const float* ln2_b  = (const float*)d_in[9];
    const float* fc1_w  = (const float*)d_in[10];
    const float* fc1_b  = (const float*)d_in[11];
    const float* fc2_w  = (const float*)d_in[12];
    const float* fc2_b  = (const float*)d_in[13];
    float* out = (float*)d_out;

    // ws layout: bf16 weights | biasmap f32 | bufA bf16 | bufQ bf16
    const int NQ = 576 * 192, NP = 192 * 192, N1 = 768 * 192, N2 = 192 * 768;
    const size_t WTOT = 2ull * (NQ + NP + N1 + N2);
    unsigned short* wq = (unsigned short*)d_ws;
    unsigned short* wp = wq + 2 * NQ;
    unsigned short* w1 = wp + 2 * NP;
    unsigned short* w2 = w1 + 2 * N1;
    float* bmap = (float*)(wq + WTOT);
    unsigned short* bufbase = (unsigned short*)(bmap + 115248);
    const size_t fixed_bytes = WTOT * 2 + 115248 * 4;

    const size_t per_win_bytes = 98ull * (192 + 768) * sizeof(unsigned short);
    int wpc = 64;
    const int cands[5] = {1024, 512, 256, 128, 64};
    for (int ci = 0; ci < 5; ++ci) {
        if (fixed_bytes + (size_t)cands[ci] * per_win_bytes <= ws_size) { wpc = cands[ci]; break; }
    }
    const int NC = 1024 / wpc;
    const int CR = 98 * wpc;
    unsigned short* bufA = bufbase;
    unsigned short* bufQ = bufA + (size_t)CR * 192;

    f2b_kernel<<<(2 * NQ + 255) / 256, 256, 0, stream>>>(qkv_w,  wq, 2 * NQ);
    f2b_kernel<<<(2 * NP + 255) / 256, 256, 0, stream>>>(proj_w, wp, 2 * NP);
    f2b_kernel<<<(2 * N1 + 255) / 256, 256, 0, stream>>>(fc1_w,  w1, 2 * N1);
    f2b_kernel<<<(2 * N2 + 255) / 256, 256, 0, stream>>>(fc2_w,  w2, 2 * N2);
    bias_kernel<<<(115248 + 255) / 256, 256, 0, stream>>>(table, bmap);

    for (int i = 0; i < 2; ++i) {
        const int shifted = (i == 1);
        const float* xsrc = (i == 0) ? x : out;
        for (int c = 0; c < NC; ++c) {
            const int row_off = c * CR;
            const int widx_off = c * wpc;
            ln_kernel<<<CR / 4, 256, 0, stream>>>(
                xsrc, ln1_g + i * 192, ln1_b + i * 192, bufA, shifted ? 2 : 1, row_off);
            gemm_kernel<<<(CR / 128) * 9, 256, 0, stream>>>(
                bufA, wq + (size_t)i * NQ, qkv_b + i * 576,
                bufQ, nullptr, 576, 192, 0, 0, 0);
            attn_kernel<<<dim3(wpc, 6), 256, 0, stream>>>(
                bufQ, bmap + (size_t)i * 57624, bufA, shifted, widx_off);
            gemm_kernel<<<(CR / 128) * 3, 256, 0, stream>>>(
                bufA, wp + (size_t)i * NP, proj_b + i * 192,
                out, xsrc, 192, 192, 2, shifted, row_off);
        }
        for (int c = 0; c < NC; ++c) {
            const int row_off = c * CR;
            ln_kernel<<<CR / 4, 256, 0, stream>>>(
                out, ln2_g + i * 192, ln2_b + i * 192, bufA, 0, row_off);
            gemm_kernel<<<(CR / 128) * 12, 256, 0, stream>>>(
                bufA, w1 + (size_t)i * N1, fc1_b + i * 768,
                bufQ, nullptr, 768, 192, 1, 0, 0);
            gemm_kernel<<<(CR / 128) * 3, 256, 0, stream>>>(
                bufQ, w2 + (size_t)i * N2, fc2_b + i * 192,
                out + (size_t)row_off * 192, out + (size_t)row_off * 192,
                192, 768, 3, 0, 0);
        }
    }
}

// Round 6
// 1023.010 us; speedup vs baseline: 4.1445x; 1.1553x over previous
//
#include <hip/hip_runtime.h>
#include <math.h>

#define T_TOKENS 100352

typedef short s16x8 __attribute__((ext_vector_type(8)));
typedef float f32x4 __attribute__((ext_vector_type(4)));

__device__ __forceinline__ unsigned short f2b(float f) {
    union { float f; unsigned u; } x; x.f = f;
    unsigned r = x.u + 0x7fffu + ((x.u >> 16) & 1u);   // RNE
    return (unsigned short)(r >> 16);
}
__device__ __forceinline__ float b2f(unsigned short h) {
    union { unsigned u; float f; } x; x.u = (unsigned)h << 16;
    return x.f;
}

#define GLOAD_LDS16(gsrc, ldst) __builtin_amdgcn_global_load_lds( \
    (const __attribute__((address_space(1))) void*)(gsrc), \
    (__attribute__((address_space(3))) void*)(ldst), 16, 0, 0)

// Map window-layout row r (widx*98 + n) to flat token index. Self-inverse
// pairing: gather (LN) and scatter (proj) use the same mapping.
__device__ __forceinline__ int win_row_to_token(int r, int shifted) {
    int widx = r / 98;
    int n = r - widx * 98;
    int b = widx >> 9;
    int remw = widx & 511;
    int dW = remw >> 6, hW = (remw >> 3) & 7, wW = remw & 7;
    int zd = n / 49;
    int nr = n - zd * 49;
    int zh = nr / 7, zw = nr - zh * 7;
    int d = dW * 2 + zd, h = hW * 7 + zh, w = wW * 7 + zw;
    if (shifted) {
        d = (d + 1) & 15;
        h += 3; if (h >= 56) h -= 56;
        w += 3; if (w >= 56) w -= 56;
    }
    return ((b * 16 + d) * 56 + h) * 56 + w;
}

__global__ __launch_bounds__(256) void f2b_kernel(
    const float* __restrict__ in, unsigned short* __restrict__ out, int n)
{
    int i = blockIdx.x * 256 + threadIdx.x;
    if (i < n) out[i] = f2b(in[i]);
}

// Combined bias+mask map, pre-scaled by log2(e), bf16.
// bmc[l][cls][h][q][kv]: cls bits = (dW==7)<<2 | (hW==7)<<1 | (wW==7).
// total = 2 * 8 * 6 * 98 * 98 = 921984
__global__ __launch_bounds__(256) void bias_kernel(
    const float* __restrict__ table, unsigned short* __restrict__ bmc)
{
    int idx = blockIdx.x * 256 + threadIdx.x;
    if (idx >= 921984) return;
    int l = idx / 460992;
    int r = idx - l * 460992;
    int cls = r / 57624;
    int r2 = r - cls * 57624;
    int h = r2 / 9604;
    int e = r2 - h * 9604;
    int n = e / 98, m = e - n * 98;
    int zd = n / 49, nr = n - zd * 49, zh = nr / 7, zw = nr - zh * 7;
    int yd = m / 49, mr = m - yd * 49, yh = mr / 7, yw = mr - yh * 7;
    int rpi = (zd - yd + 1) * 169 + (zh - yh + 6) * 13 + (zw - yw + 6);
    float v = table[l * 3042 + rpi * 6 + h];
    int rn = (((cls >> 2) & 1) ? 1 + zd : 0) * 9
           + (((cls >> 1) & 1) ? (zh < 4 ? 1 : 2) : 0) * 3
           + ((cls & 1) ? (zw < 4 ? 1 : 2) : 0);
    int rm2 = (((cls >> 2) & 1) ? 1 + yd : 0) * 9
            + (((cls >> 1) & 1) ? (yh < 4 ? 1 : 2) : 0) * 3
            + ((cls & 1) ? (yw < 4 ? 1 : 2) : 0);
    if (rn != rm2) v += 2.0f;
    bmc[idx] = f2b(v * 1.4426950408889634f);
}

// LayerNorm over C=192 -> bf16 out. mode 0: linear; 1: window gather; 2: shifted gather.
__global__ __launch_bounds__(256) void ln_kernel(
    const float* __restrict__ x, const float* __restrict__ g,
    const float* __restrict__ b, unsigned short* __restrict__ out, int mode, int row_off)
{
    int r = blockIdx.x * 4 + (threadIdx.x >> 6);
    int lane = threadIdx.x & 63;
    int t = (mode == 0) ? (row_off + r) : win_row_to_token(row_off + r, mode == 2);
    const float* xp = x + (size_t)t * 192;
    float v0 = xp[lane], v1 = xp[lane + 64], v2 = xp[lane + 128];
    float s = v0 + v1 + v2;
    float sq = v0 * v0 + v1 * v1 + v2 * v2;
    #pragma unroll
    for (int off = 32; off; off >>= 1) {
        s += __shfl_xor(s, off);
        sq += __shfl_xor(sq, off);
    }
    float mu = s * (1.0f / 192.0f);
    float var = sq * (1.0f / 192.0f) - mu * mu;
    float rs = rsqrtf(var + 1e-5f);
    unsigned short* op = out + (size_t)r * 192;
    op[lane]       = f2b((v0 - mu) * rs * g[lane]       + b[lane]);
    op[lane + 64]  = f2b((v1 - mu) * rs * g[lane + 64]  + b[lane + 64]);
    op[lane + 128] = f2b((v2 - mu) * rs * g[lane + 128] + b[lane + 128]);
}

// bf16 MFMA GEMM: out[M,N] = A[M,K] @ Wb[N,K]^T + bias.
// Tile 128x96, BK=64, 4 waves in 2x2 (each wave 64x48).
// ep 0: bias -> bf16   ep 1: bias+GELU -> bf16
// ep 2: bias+residual scatter -> f32   ep 3: bias+residual linear -> f32
__global__ __launch_bounds__(256) void gemm_kernel(
    const unsigned short* __restrict__ A, const unsigned short* __restrict__ Wb,
    const float* __restrict__ bias, void* outp, const float* resx,
    int N, int K, int ep, int shifted, int row_off)
{
    __shared__ short As[128 * 64];
    __shared__ short Bs[96 * 64];
    const int ntiles = N / 96;
    const int bm = blockIdx.x / ntiles;
    const int bn = blockIdx.x - bm * ntiles;
    const int r0 = bm << 7, n0 = bn * 96;
    const int tid = threadIdx.x;
    const int wid = tid >> 6, lane = tid & 63;
    const int wrow = (wid >> 1) << 6;   // 0 / 64
    const int wcol = (wid & 1) * 48;    // 0 / 48
    const int srow = lane >> 3;
    const int sslot = lane & 7;

    f32x4 acc[4][3];
    #pragma unroll
    for (int mi = 0; mi < 4; ++mi)
        #pragma unroll
        for (int ni = 0; ni < 3; ++ni)
            acc[mi][ni] = (f32x4){0.f, 0.f, 0.f, 0.f};

    for (int k0 = 0; k0 < K; k0 += 64) {
        #pragma unroll
        for (int g = 0; g < 4; ++g) {
            int row = wid * 32 + g * 8 + srow;
            const unsigned short* src =
                A + (size_t)(r0 + row) * K + k0 + ((sslot ^ (row & 7)) << 3);
            GLOAD_LDS16(src, &As[(wid * 32 + g * 8) * 64]);
        }
        #pragma unroll
        for (int g = 0; g < 3; ++g) {
            int row = wid * 24 + g * 8 + srow;
            const unsigned short* src =
                Wb + (size_t)(n0 + row) * K + k0 + ((sslot ^ (row & 7)) << 3);
            GLOAD_LDS16(src, &Bs[(wid * 24 + g * 8) * 64]);
        }
        __syncthreads();
        #pragma unroll
        for (int ks = 0; ks < 2; ++ks) {
            const int q = ks * 4 + (lane >> 4);
            s16x8 bfr[3];
            #pragma unroll
            for (int ni = 0; ni < 3; ++ni) {
                int col = wcol + ni * 16 + (lane & 15);
                bfr[ni] = *(const s16x8*)&Bs[col * 64 + ((q ^ (col & 7)) << 3)];
            }
            #pragma unroll
            for (int mi = 0; mi < 4; ++mi) {
                int row = wrow + mi * 16 + (lane & 15);
                s16x8 afr = *(const s16x8*)&As[row * 64 + ((q ^ (row & 7)) << 3)];
                #pragma unroll
                for (int ni = 0; ni < 3; ++ni)
                    acc[mi][ni] = __builtin_amdgcn_mfma_f32_16x16x32_bf16(
                        afr, bfr[ni], acc[mi][ni], 0, 0, 0);
            }
        }
        __syncthreads();
    }

    #pragma unroll
    for (int mi = 0; mi < 4; ++mi) {
        #pragma unroll
        for (int ni = 0; ni < 3; ++ni) {
            int colg = n0 + wcol + ni * 16 + (lane & 15);
            float bv = bias[colg];
            #pragma unroll
            for (int rg = 0; rg < 4; ++rg) {
                int rowl = r0 + wrow + mi * 16 + ((lane >> 4) << 2) + rg;
                float v = acc[mi][ni][rg] + bv;
                if (ep == 0) {
                    ((unsigned short*)outp)[(size_t)rowl * N + colg] = f2b(v);
                } else if (ep == 1) {
                    v = 0.5f * v * (1.0f + erff(v * 0.70710678118654752f));
                    ((unsigned short*)outp)[(size_t)rowl * N + colg] = f2b(v);
                } else {
                    int t = (ep == 2) ? win_row_to_token(row_off + rowl, shifted) : rowl;
                    size_t o = (size_t)t * 192 + colg;
                    ((float*)outp)[o] = resx[o] + v;
                }
            }
        }
    }
}

// MFMA attention, in-register softmax (exp2 domain), class-combined bias+mask.
__global__ __launch_bounds__(256, 4) void attn_kernel(
    const unsigned short* __restrict__ qkv, const unsigned short* __restrict__ bmc,
    unsigned short* __restrict__ out, int shifted, int widx_off)
{
    __shared__ __align__(16) short QKP[112 * 136];
    __shared__ __align__(16) short Vt[32 * 136];

    const int wloc = blockIdx.x;
    const int head = blockIdx.y;
    const int tid = threadIdx.x;
    const int wid = tid >> 6, lane = tid & 63;
    const int r0 = wloc * 98;
    const float scale2 = 0.17677669529663687f * 1.4426950408889634f;

    short* Qs = QKP;
    short* Ks = QKP + 112 * 40;

    const int remw = (widx_off + wloc) & 511;
    const int dW = remw >> 6, hW = (remw >> 3) & 7, wW = remw & 7;
    const int cls = shifted ? (((dW == 7) << 2) | ((hW == 7) << 1) | (wW == 7)) : 0;
    const unsigned short* bmch = bmc + ((size_t)cls * 6 + head) * 9604;

    // stage Q,K row-major [112][40]; V transposed [32][136]
    for (int idx = tid; idx < 1568; idx += 256) {
        int n = idx >> 4, dp = idx & 15;
        size_t base = (size_t)(r0 + n) * 576 + head * 32 + dp * 2;
        unsigned qv = *(const unsigned*)&qkv[base];
        unsigned kv = *(const unsigned*)&qkv[base + 192];
        unsigned vv = *(const unsigned*)&qkv[base + 384];
        ((unsigned*)Qs)[n * 20 + dp] = qv;
        ((unsigned*)Ks)[n * 20 + dp] = kv;
        ((unsigned short*)Vt)[(2 * dp) * 136 + n]     = (unsigned short)(vv & 0xffff);
        ((unsigned short*)Vt)[(2 * dp + 1) * 136 + n] = (unsigned short)(vv >> 16);
    }
    for (int idx = tid; idx < 960; idx += 256) {
        int dd = idx / 30, kvp = 98 + (idx - (idx / 30) * 30);
        ((unsigned short*)Vt)[dd * 136 + kvp] = 0;
    }
    __syncthreads();

    // QK^T + combined bias/mask + in-register softmax (exp2 domain).
    unsigned pk[2][7][2];
    #pragma unroll
    for (int t = 0; t < 2; ++t) {
        int mt = wid + 4 * t;
        if (mt < 7) {
            s16x8 qa = *(const s16x8*)&Qs[(mt * 16 + (lane & 15)) * 40 + ((lane >> 4) << 3)];
            f32x4 sacc[7];
            #pragma unroll
            for (int nt = 0; nt < 7; ++nt) {
                s16x8 kb = *(const s16x8*)&Ks[(nt * 16 + (lane & 15)) * 40 + ((lane >> 4) << 3)];
                sacc[nt] = __builtin_amdgcn_mfma_f32_16x16x32_bf16(
                    qa, kb, (f32x4){0.f, 0.f, 0.f, 0.f}, 0, 0, 0);
            }
            const int kvc = lane & 15;
            #pragma unroll
            for (int nt = 0; nt < 7; ++nt) {
                int kv = nt * 16 + kvc;
                #pragma unroll
                for (int rg = 0; rg < 4; ++rg) {
                    int q = mt * 16 + ((lane >> 4) << 2) + rg;
                    float val = -1e30f;
                    if (q < 98 && kv < 98)
                        val = fmaf(sacc[nt][rg], scale2, b2f(bmch[q * 98 + kv]));
                    sacc[nt][rg] = val;
                }
            }
            #pragma unroll
            for (int rg = 0; rg < 4; ++rg) {
                float mx = sacc[0][rg];
                #pragma unroll
                for (int nt = 1; nt < 7; ++nt) mx = fmaxf(mx, sacc[nt][rg]);
                #pragma unroll
                for (int off = 1; off < 16; off <<= 1) mx = fmaxf(mx, __shfl_xor(mx, off));
                float sum = 0.f;
                #pragma unroll
                for (int nt = 0; nt < 7; ++nt) {
                    float e = exp2f(sacc[nt][rg] - mx);
                    sacc[nt][rg] = e;
                    sum += e;
                }
                #pragma unroll
                for (int off = 1; off < 16; off <<= 1) sum += __shfl_xor(sum, off);
                float inv = 1.0f / sum;
                #pragma unroll
                for (int nt = 0; nt < 7; ++nt) sacc[nt][rg] *= inv;
            }
            #pragma unroll
            for (int nt = 0; nt < 7; ++nt) {
                pk[t][nt][0] = (unsigned)f2b(sacc[nt][0]) | ((unsigned)f2b(sacc[nt][1]) << 16);
                pk[t][nt][1] = (unsigned)f2b(sacc[nt][2]) | ((unsigned)f2b(sacc[nt][3]) << 16);
            }
        }
    }
    __syncthreads();   // all Q/K reads complete; safe to overwrite with P

    unsigned short* P = (unsigned short*)QKP;
    #pragma unroll
    for (int t = 0; t < 2; ++t) {
        int mt = wid + 4 * t;
        if (mt < 7) {
            int qb = mt * 16 + ((lane >> 4) << 2);
            #pragma unroll
            for (int nt = 0; nt < 7; ++nt) {
                P[(qb + 0) * 136 + nt * 16 + (lane & 15)] = (unsigned short)(pk[t][nt][0] & 0xffff);
                P[(qb + 1) * 136 + nt * 16 + (lane & 15)] = (unsigned short)(pk[t][nt][0] >> 16);
                P[(qb + 2) * 136 + nt * 16 + (lane & 15)] = (unsigned short)(pk[t][nt][1] & 0xffff);
                P[(qb + 3) * 136 + nt * 16 + (lane & 15)] = (unsigned short)(pk[t][nt][1] >> 16);
            }
            #pragma unroll
            for (int rg = 0; rg < 4; ++rg)
                P[(qb + rg) * 136 + 112 + (lane & 15)] = 0;
        }
    }
    __syncthreads();

    // PV: O[q][dd] = sum_kv P[q][kv] * V[kv][dd]
    #pragma unroll
    for (int t = 0; t < 2; ++t) {
        int mt = wid + 4 * t;
        if (mt < 7) {
            f32x4 o0 = {0.f, 0.f, 0.f, 0.f}, o1 = {0.f, 0.f, 0.f, 0.f};
            const short* prow = (const short*)&P[(mt * 16 + (lane & 15)) * 136 + ((lane >> 4) << 3)];
            #pragma unroll
            for (int ks = 0; ks < 4; ++ks) {
                s16x8 pa = *(const s16x8*)&prow[ks * 32];
                s16x8 vb0 = *(const s16x8*)&Vt[(lane & 15) * 136 + ks * 32 + ((lane >> 4) << 3)];
                s16x8 vb1 = *(const s16x8*)&Vt[((lane & 15) + 16) * 136 + ks * 32 + ((lane >> 4) << 3)];
                o0 = __builtin_amdgcn_mfma_f32_16x16x32_bf16(pa, vb0, o0, 0, 0, 0);
                o1 = __builtin_amdgcn_mfma_f32_16x16x32_bf16(pa, vb1, o1, 0, 0, 0);
            }
            #pragma unroll
            for (int rg = 0; rg < 4; ++rg) {
                int q = mt * 16 + ((lane >> 4) << 2) + rg;
                if (q < 98) {
                    size_t ob = (size_t)(r0 + q) * 192 + head * 32;
                    out[ob + (lane & 15)]      = f2b(o0[rg]);
                    out[ob + 16 + (lane & 15)] = f2b(o1[rg]);
                }
            }
        }
    }
}

extern "C" void kernel_launch(void* const* d_in, const int* in_sizes, int n_in,
                              void* d_out, int out_size, void* d_ws, size_t ws_size,
                              hipStream_t stream) {
    (void)in_sizes; (void)n_in; (void)out_size;
    const float* x      = (const float*)d_in[0];
    const float* ln1_g  = (const float*)d_in[1];
    const float* ln1_b  = (const float*)d_in[2];
    const float* qkv_w  = (const float*)d_in[3];
    const float* qkv_b  = (const float*)d_in[4];
    const float* proj_w = (const float*)d_in[5];
    const float* proj_b = (const float*)d_in[6];
    const float* table  = (const float*)d_in[7];
    const float* ln2_g  = (const float*)d_in[8];
    const float* ln2_b  = (const float*)d_in[9];
    const float* fc1_w  = (const float*)d_in[10];
    const float* fc1_b  = (const float*)d_in[11];
    const float* fc2_w  = (const float*)d_in[12];
    const float* fc2_b  = (const float*)d_in[13];
    float* out = (float*)d_out;

    // ws layout: bf16 weights | bmc bf16 | bufA bf16 | bufQ bf16
    const int NQ = 576 * 192, NP = 192 * 192, N1 = 768 * 192, N2 = 192 * 768;
    const size_t WTOT = 2ull * (NQ + NP + N1 + N2);
    unsigned short* wq = (unsigned short*)d_ws;
    unsigned short* wp = wq + 2 * NQ;
    unsigned short* w1 = wp + 2 * NP;
    unsigned short* w2 = w1 + 2 * N1;
    unsigned short* bmc = wq + WTOT;
    unsigned short* bufbase = bmc + 921984;
    const size_t fixed_bytes = (WTOT + 921984) * 2;

    const size_t per_win_bytes = 98ull * (192 + 768) * sizeof(unsigned short);
    int wpc = 64;
    const int cands[5] = {1024, 512, 256, 128, 64};
    for (int ci = 0; ci < 5; ++ci) {
        if (fixed_bytes + (size_t)cands[ci] * per_win_bytes <= ws_size) { wpc = cands[ci]; break; }
    }
    const int NC = 1024 / wpc;
    const int CR = 98 * wpc;
    unsigned short* bufA = bufbase;
    unsigned short* bufQ = bufA + (size_t)CR * 192;

    f2b_kernel<<<(2 * NQ + 255) / 256, 256, 0, stream>>>(qkv_w,  wq, 2 * NQ);
    f2b_kernel<<<(2 * NP + 255) / 256, 256, 0, stream>>>(proj_w, wp, 2 * NP);
    f2b_kernel<<<(2 * N1 + 255) / 256, 256, 0, stream>>>(fc1_w,  w1, 2 * N1);
    f2b_kernel<<<(2 * N2 + 255) / 256, 256, 0, stream>>>(fc2_w,  w2, 2 * N2);
    bias_kernel<<<(921984 + 255) / 256, 256, 0, stream>>>(table, bmc);

    for (int i = 0; i < 2; ++i) {
        const int shifted = (i == 1);
        const float* xsrc = (i == 0) ? x : out;
        for (int c = 0; c < NC; ++c) {
            const int row_off = c * CR;
            const int widx_off = c * wpc;
            ln_kernel<<<CR / 4, 256, 0, stream>>>(
                xsrc, ln1_g + i * 192, ln1_b + i * 192, bufA, shifted ? 2 : 1, row_off);
            gemm_kernel<<<(CR / 128) * 6, 256, 0, stream>>>(
                bufA, wq + (size_t)i * NQ, qkv_b + i * 576,
                bufQ, nullptr, 576, 192, 0, 0, 0);
            attn_kernel<<<dim3(wpc, 6), 256, 0, stream>>>(
                bufQ, bmc + (size_t)i * 460992, bufA, shifted, widx_off);
            gemm_kernel<<<(CR / 128) * 2, 256, 0, stream>>>(
                bufA, wp + (size_t)i * NP, proj_b + i * 192,
                out, xsrc, 192, 192, 2, shifted, row_off);
        }
        for (int c = 0; c < NC; ++c) {
            const int row_off = c * CR;
            ln_kernel<<<CR / 4, 256, 0, stream>>>(
                out, ln2_g + i * 192, ln2_b + i * 192, bufA, 0, row_off);
            gemm_kernel<<<(CR / 128) * 8, 256, 0, stream>>>(
                bufA, w1 + (size_t)i * N1, fc1_b + i * 768,
                bufQ, nullptr, 768, 192, 1, 0, 0);
            gemm_kernel<<<(CR / 128) * 2, 256, 0, stream>>>(
                bufQ, w2 + (size_t)i * N2, fc2_b + i * 192,
                out + (size_t)row_off * 192, out + (size_t)row_off * 192,
                192, 768, 3, 0, 0);
        }
    }
}

// Round 7
// 970.905 us; speedup vs baseline: 4.3669x; 1.0537x over previous
//
#include <hip/hip_runtime.h>
#include <math.h>

#define T_TOKENS 100352

typedef short s16x8 __attribute__((ext_vector_type(8)));
typedef float f32x4 __attribute__((ext_vector_type(4)));

__device__ __forceinline__ unsigned short f2b(float f) {
    union { float f; unsigned u; } x; x.f = f;
    unsigned r = x.u + 0x7fffu + ((x.u >> 16) & 1u);   // RNE
    return (unsigned short)(r >> 16);
}
__device__ __forceinline__ float b2f(unsigned short h) {
    union { unsigned u; float f; } x; x.u = (unsigned)h << 16;
    return x.f;
}

#define GLOAD_LDS16(gsrc, ldst) __builtin_amdgcn_global_load_lds( \
    (const __attribute__((address_space(1))) void*)(gsrc), \
    (__attribute__((address_space(3))) void*)(ldst), 16, 0, 0)

// Map window-layout row r (widx*98 + n) to flat token index. Self-inverse
// pairing: gather (LN) and scatter (proj) use the same mapping.
__device__ __forceinline__ int win_row_to_token(int r, int shifted) {
    int widx = r / 98;
    int n = r - widx * 98;
    int b = widx >> 9;
    int remw = widx & 511;
    int dW = remw >> 6, hW = (remw >> 3) & 7, wW = remw & 7;
    int zd = n / 49;
    int nr = n - zd * 49;
    int zh = nr / 7, zw = nr - zh * 7;
    int d = dW * 2 + zd, h = hW * 7 + zh, w = wW * 7 + zw;
    if (shifted) {
        d = (d + 1) & 15;
        h += 3; if (h >= 56) h -= 56;
        w += 3; if (w >= 56) w -= 56;
    }
    return ((b * 16 + d) * 56 + h) * 56 + w;
}

__global__ __launch_bounds__(256) void f2b_kernel(
    const float* __restrict__ in, unsigned short* __restrict__ out, int n)
{
    int i = blockIdx.x * 256 + threadIdx.x;
    if (i < n) out[i] = f2b(in[i]);
}

// Combined bias+mask map, pre-scaled by log2(e), bf16.
// bmc[l][cls][h][q][kv]: cls bits = (dW==7)<<2 | (hW==7)<<1 | (wW==7).
__global__ __launch_bounds__(256) void bias_kernel(
    const float* __restrict__ table, unsigned short* __restrict__ bmc)
{
    int idx = blockIdx.x * 256 + threadIdx.x;
    if (idx >= 921984) return;
    int l = idx / 460992;
    int r = idx - l * 460992;
    int cls = r / 57624;
    int r2 = r - cls * 57624;
    int h = r2 / 9604;
    int e = r2 - h * 9604;
    int n = e / 98, m = e - n * 98;
    int zd = n / 49, nr = n - zd * 49, zh = nr / 7, zw = nr - zh * 7;
    int yd = m / 49, mr = m - yd * 49, yh = mr / 7, yw = mr - yh * 7;
    int rpi = (zd - yd + 1) * 169 + (zh - yh + 6) * 13 + (zw - yw + 6);
    float v = table[l * 3042 + rpi * 6 + h];
    int rn = (((cls >> 2) & 1) ? 1 + zd : 0) * 9
           + (((cls >> 1) & 1) ? (zh < 4 ? 1 : 2) : 0) * 3
           + ((cls & 1) ? (zw < 4 ? 1 : 2) : 0);
    int rm2 = (((cls >> 2) & 1) ? 1 + yd : 0) * 9
            + (((cls >> 1) & 1) ? (yh < 4 ? 1 : 2) : 0) * 3
            + ((cls & 1) ? (yw < 4 ? 1 : 2) : 0);
    if (rn != rm2) v += 2.0f;
    bmc[idx] = f2b(v * 1.4426950408889634f);
}

// LayerNorm over C=192 -> bf16 out. mode 0: linear; 1: window gather; 2: shifted gather.
__global__ __launch_bounds__(256) void ln_kernel(
    const float* __restrict__ x, const float* __restrict__ g,
    const float* __restrict__ b, unsigned short* __restrict__ out, int mode, int row_off)
{
    int r = blockIdx.x * 4 + (threadIdx.x >> 6);
    int lane = threadIdx.x & 63;
    int t = (mode == 0) ? (row_off + r) : win_row_to_token(row_off + r, mode == 2);
    const float* xp = x + (size_t)t * 192;
    float v0 = xp[lane], v1 = xp[lane + 64], v2 = xp[lane + 128];
    float s = v0 + v1 + v2;
    float sq = v0 * v0 + v1 * v1 + v2 * v2;
    #pragma unroll
    for (int off = 32; off; off >>= 1) {
        s += __shfl_xor(s, off);
        sq += __shfl_xor(sq, off);
    }
    float mu = s * (1.0f / 192.0f);
    float var = sq * (1.0f / 192.0f) - mu * mu;
    float rs = rsqrtf(var + 1e-5f);
    unsigned short* op = out + (size_t)r * 192;
    op[lane]       = f2b((v0 - mu) * rs * g[lane]       + b[lane]);
    op[lane + 64]  = f2b((v1 - mu) * rs * g[lane + 64]  + b[lane + 64]);
    op[lane + 128] = f2b((v2 - mu) * rs * g[lane + 128] + b[lane + 128]);
}

// bf16 MFMA GEMM: out[M,N] = A[M,K] @ Wb[N,K]^T + bias.
// Tile 128x96, BK=64, 4 waves 2x2 (each wave 64x48).
// XCD-pinning swizzle: all bn of a bm land on one XCD (L2 A-reuse + write merge).
// ep 0: bias -> bf16   ep 1: bias+GELU(tanh approx) -> bf16
// ep 2: bias+residual scatter -> f32   ep 3: bias+residual linear -> f32
__global__ __launch_bounds__(256) void gemm_kernel(
    const unsigned short* __restrict__ A, const unsigned short* __restrict__ Wb,
    const float* __restrict__ bias, void* outp, const float* resx,
    int N, int K, int ep, int shifted, int row_off)
{
    __shared__ short As[128 * 64];
    __shared__ short Bs[96 * 64];
    const int ntiles = N / 96;
    const int NB = gridDim.x;
    int L = blockIdx.x;
    if ((NB & 7) == 0) {                 // bijective XCD-chunk swizzle (xcd = id%8)
        L = (blockIdx.x & 7) * (NB >> 3) + (blockIdx.x >> 3);
    }
    const int bm = L / ntiles;
    const int bn = L - bm * ntiles;
    const int r0 = bm << 7, n0 = bn * 96;
    const int tid = threadIdx.x;
    const int wid = tid >> 6, lane = tid & 63;
    const int wrow = (wid >> 1) << 6;   // 0 / 64
    const int wcol = (wid & 1) * 48;    // 0 / 48
    const int srow = lane >> 3;
    const int sslot = lane & 7;

    f32x4 acc[4][3];
    #pragma unroll
    for (int mi = 0; mi < 4; ++mi)
        #pragma unroll
        for (int ni = 0; ni < 3; ++ni)
            acc[mi][ni] = (f32x4){0.f, 0.f, 0.f, 0.f};

    for (int k0 = 0; k0 < K; k0 += 64) {
        #pragma unroll
        for (int g = 0; g < 4; ++g) {
            int row = wid * 32 + g * 8 + srow;
            const unsigned short* src =
                A + (size_t)(r0 + row) * K + k0 + ((sslot ^ (row & 7)) << 3);
            GLOAD_LDS16(src, &As[(wid * 32 + g * 8) * 64]);
        }
        #pragma unroll
        for (int g = 0; g < 3; ++g) {
            int row = wid * 24 + g * 8 + srow;
            const unsigned short* src =
                Wb + (size_t)(n0 + row) * K + k0 + ((sslot ^ (row & 7)) << 3);
            GLOAD_LDS16(src, &Bs[(wid * 24 + g * 8) * 64]);
        }
        __syncthreads();
        #pragma unroll
        for (int ks = 0; ks < 2; ++ks) {
            const int q = ks * 4 + (lane >> 4);
            s16x8 bfr[3];
            #pragma unroll
            for (int ni = 0; ni < 3; ++ni) {
                int col = wcol + ni * 16 + (lane & 15);
                bfr[ni] = *(const s16x8*)&Bs[col * 64 + ((q ^ (col & 7)) << 3)];
            }
            #pragma unroll
            for (int mi = 0; mi < 4; ++mi) {
                int row = wrow + mi * 16 + (lane & 15);
                s16x8 afr = *(const s16x8*)&As[row * 64 + ((q ^ (row & 7)) << 3)];
                #pragma unroll
                for (int ni = 0; ni < 3; ++ni)
                    acc[mi][ni] = __builtin_amdgcn_mfma_f32_16x16x32_bf16(
                        afr, bfr[ni], acc[mi][ni], 0, 0, 0);
            }
        }
        __syncthreads();
    }

    #pragma unroll
    for (int mi = 0; mi < 4; ++mi) {
        #pragma unroll
        for (int ni = 0; ni < 3; ++ni) {
            int colg = n0 + wcol + ni * 16 + (lane & 15);
            float bv = bias[colg];
            #pragma unroll
            for (int rg = 0; rg < 4; ++rg) {
                int rowl = r0 + wrow + mi * 16 + ((lane >> 4) << 2) + rg;
                float v = acc[mi][ni][rg] + bv;
                if (ep == 0) {
                    ((unsigned short*)outp)[(size_t)rowl * N + colg] = f2b(v);
                } else if (ep == 1) {
                    // GELU, tanh form via exp2: gelu = v * z/(z+1), z = e^{2y}
                    float y = 0.7978845608028654f * fmaf(0.044715f * v, v * v, v);
                    y = fminf(fmaxf(y, -15.f), 15.f);
                    float z = exp2f(2.8853900817779268f * y);
                    v = v * z / (z + 1.0f);
                    ((unsigned short*)outp)[(size_t)rowl * N + colg] = f2b(v);
                } else {
                    int t = (ep == 2) ? win_row_to_token(row_off + rowl, shifted) : rowl;
                    size_t o = (size_t)t * 192 + colg;
                    ((float*)outp)[o] = resx[o] + v;
                }
            }
        }
    }
}

// MFMA attention, in-register softmax (exp2 domain), class-combined bias+mask.
__global__ __launch_bounds__(256, 4) void attn_kernel(
    const unsigned short* __restrict__ qkv, const unsigned short* __restrict__ bmc,
    unsigned short* __restrict__ out, int shifted, int widx_off)
{
    __shared__ __align__(16) short QKP[112 * 136];
    __shared__ __align__(16) short Vt[32 * 136];

    const int wloc = blockIdx.x;
    const int head = blockIdx.y;
    const int tid = threadIdx.x;
    const int wid = tid >> 6, lane = tid & 63;
    const int r0 = wloc * 98;
    const float scale2 = 0.17677669529663687f * 1.4426950408889634f;

    short* Qs = QKP;
    short* Ks = QKP + 112 * 40;

    const int remw = (widx_off + wloc) & 511;
    const int dW = remw >> 6, hW = (remw >> 3) & 7, wW = remw & 7;
    const int cls = shifted ? (((dW == 7) << 2) | ((hW == 7) << 1) | (wW == 7)) : 0;
    const unsigned short* bmch = bmc + ((size_t)cls * 6 + head) * 9604;

    for (int idx = tid; idx < 1568; idx += 256) {
        int n = idx >> 4, dp = idx & 15;
        size_t base = (size_t)(r0 + n) * 576 + head * 32 + dp * 2;
        unsigned qv = *(const unsigned*)&qkv[base];
        unsigned kv = *(const unsigned*)&qkv[base + 192];
        unsigned vv = *(const unsigned*)&qkv[base + 384];
        ((unsigned*)Qs)[n * 20 + dp] = qv;
        ((unsigned*)Ks)[n * 20 + dp] = kv;
        ((unsigned short*)Vt)[(2 * dp) * 136 + n]     = (unsigned short)(vv & 0xffff);
        ((unsigned short*)Vt)[(2 * dp + 1) * 136 + n] = (unsigned short)(vv >> 16);
    }
    for (int idx = tid; idx < 960; idx += 256) {
        int dd = idx / 30, kvp = 98 + (idx - (idx / 30) * 30);
        ((unsigned short*)Vt)[dd * 136 + kvp] = 0;
    }
    __syncthreads();

    unsigned pk[2][7][2];
    #pragma unroll
    for (int t = 0; t < 2; ++t) {
        int mt = wid + 4 * t;
        if (mt < 7) {
            s16x8 qa = *(const s16x8*)&Qs[(mt * 16 + (lane & 15)) * 40 + ((lane >> 4) << 3)];
            f32x4 sacc[7];
            #pragma unroll
            for (int nt = 0; nt < 7; ++nt) {
                s16x8 kb = *(const s16x8*)&Ks[(nt * 16 + (lane & 15)) * 40 + ((lane >> 4) << 3)];
                sacc[nt] = __builtin_amdgcn_mfma_f32_16x16x32_bf16(
                    qa, kb, (f32x4){0.f, 0.f, 0.f, 0.f}, 0, 0, 0);
            }
            const int kvc = lane & 15;
            #pragma unroll
            for (int nt = 0; nt < 7; ++nt) {
                int kv = nt * 16 + kvc;
                #pragma unroll
                for (int rg = 0; rg < 4; ++rg) {
                    int q = mt * 16 + ((lane >> 4) << 2) + rg;
                    float val = -1e30f;
                    if (q < 98 && kv < 98)
                        val = fmaf(sacc[nt][rg], scale2, b2f(bmch[q * 98 + kv]));
                    sacc[nt][rg] = val;
                }
            }
            #pragma unroll
            for (int rg = 0; rg < 4; ++rg) {
                float mx = sacc[0][rg];
                #pragma unroll
                for (int nt = 1; nt < 7; ++nt) mx = fmaxf(mx, sacc[nt][rg]);
                #pragma unroll
                for (int off = 1; off < 16; off <<= 1) mx = fmaxf(mx, __shfl_xor(mx, off));
                float sum = 0.f;
                #pragma unroll
                for (int nt = 0; nt < 7; ++nt) {
                    float e = exp2f(sacc[nt][rg] - mx);
                    sacc[nt][rg] = e;
                    sum += e;
                }
                #pragma unroll
                for (int off = 1; off < 16; off <<= 1) sum += __shfl_xor(sum, off);
                float inv = 1.0f / sum;
                #pragma unroll
                for (int nt = 0; nt < 7; ++nt) sacc[nt][rg] *= inv;
            }
            #pragma unroll
            for (int nt = 0; nt < 7; ++nt) {
                pk[t][nt][0] = (unsigned)f2b(sacc[nt][0]) | ((unsigned)f2b(sacc[nt][1]) << 16);
                pk[t][nt][1] = (unsigned)f2b(sacc[nt][2]) | ((unsigned)f2b(sacc[nt][3]) << 16);
            }
        }
    }
    __syncthreads();

    unsigned short* P = (unsigned short*)QKP;
    #pragma unroll
    for (int t = 0; t < 2; ++t) {
        int mt = wid + 4 * t;
        if (mt < 7) {
            int qb = mt * 16 + ((lane >> 4) << 2);
            #pragma unroll
            for (int nt = 0; nt < 7; ++nt) {
                P[(qb + 0) * 136 + nt * 16 + (lane & 15)] = (unsigned short)(pk[t][nt][0] & 0xffff);
                P[(qb + 1) * 136 + nt * 16 + (lane & 15)] = (unsigned short)(pk[t][nt][0] >> 16);
                P[(qb + 2) * 136 + nt * 16 + (lane & 15)] = (unsigned short)(pk[t][nt][1] & 0xffff);
                P[(qb + 3) * 136 + nt * 16 + (lane & 15)] = (unsigned short)(pk[t][nt][1] >> 16);
            }
            #pragma unroll
            for (int rg = 0; rg < 4; ++rg)
                P[(qb + rg) * 136 + 112 + (lane & 15)] = 0;
        }
    }
    __syncthreads();

    #pragma unroll
    for (int t = 0; t < 2; ++t) {
        int mt = wid + 4 * t;
        if (mt < 7) {
            f32x4 o0 = {0.f, 0.f, 0.f, 0.f}, o1 = {0.f, 0.f, 0.f, 0.f};
            const short* prow = (const short*)&P[(mt * 16 + (lane & 15)) * 136 + ((lane >> 4) << 3)];
            #pragma unroll
            for (int ks = 0; ks < 4; ++ks) {
                s16x8 pa = *(const s16x8*)&prow[ks * 32];
                s16x8 vb0 = *(const s16x8*)&Vt[(lane & 15) * 136 + ks * 32 + ((lane >> 4) << 3)];
                s16x8 vb1 = *(const s16x8*)&Vt[((lane & 15) + 16) * 136 + ks * 32 + ((lane >> 4) << 3)];
                o0 = __builtin_amdgcn_mfma_f32_16x16x32_bf16(pa, vb0, o0, 0, 0, 0);
                o1 = __builtin_amdgcn_mfma_f32_16x16x32_bf16(pa, vb1, o1, 0, 0, 0);
            }
            #pragma unroll
            for (int rg = 0; rg < 4; ++rg) {
                int q = mt * 16 + ((lane >> 4) << 2) + rg;
                if (q < 98) {
                    size_t ob = (size_t)(r0 + q) * 192 + head * 32;
                    out[ob + (lane & 15)]      = f2b(o0[rg]);
                    out[ob + 16 + (lane & 15)] = f2b(o1[rg]);
                }
            }
        }
    }
}

extern "C" void kernel_launch(void* const* d_in, const int* in_sizes, int n_in,
                              void* d_out, int out_size, void* d_ws, size_t ws_size,
                              hipStream_t stream) {
    (void)in_sizes; (void)n_in; (void)out_size;
    const float* x      = (const float*)d_in[0];
    const float* ln1_g  = (const float*)d_in[1];
    const float* ln1_b  = (const float*)d_in[2];
    const float* qkv_w  = (const float*)d_in[3];
    const float* qkv_b  = (const float*)d_in[4];
    const float* proj_w = (const float*)d_in[5];
    const float* proj_b = (const float*)d_in[6];
    const float* table  = (const float*)d_in[7];
    const float* ln2_g  = (const float*)d_in[8];
    const float* ln2_b  = (const float*)d_in[9];
    const float* fc1_w  = (const float*)d_in[10];
    const float* fc1_b  = (const float*)d_in[11];
    const float* fc2_w  = (const float*)d_in[12];
    const float* fc2_b  = (const float*)d_in[13];
    float* out = (float*)d_out;

    // ws layout: bf16 weights | bmc bf16 | bufA bf16 | bufQ bf16
    const int NQ = 576 * 192, NP = 192 * 192, N1 = 768 * 192, N2 = 192 * 768;
    const size_t WTOT = 2ull * (NQ + NP + N1 + N2);
    unsigned short* wq = (unsigned short*)d_ws;
    unsigned short* wp = wq + 2 * NQ;
    unsigned short* w1 = wp + 2 * NP;
    unsigned short* w2 = w1 + 2 * N1;
    unsigned short* bmc = wq + WTOT;
    unsigned short* bufbase = bmc + 921984;
    const size_t fixed_bytes = (WTOT + 921984) * 2;

    const size_t per_win_bytes = 98ull * (192 + 768) * sizeof(unsigned short);
    int wpc = 64;
    const int cands[5] = {1024, 512, 256, 128, 64};
    for (int ci = 0; ci < 5; ++ci) {
        if (fixed_bytes + (size_t)cands[ci] * per_win_bytes <= ws_size) { wpc = cands[ci]; break; }
    }
    const int NC = 1024 / wpc;
    const int CR = 98 * wpc;
    unsigned short* bufA = bufbase;
    unsigned short* bufQ = bufA + (size_t)CR * 192;

    f2b_kernel<<<(2 * NQ + 255) / 256, 256, 0, stream>>>(qkv_w,  wq, 2 * NQ);
    f2b_kernel<<<(2 * NP + 255) / 256, 256, 0, stream>>>(proj_w, wp, 2 * NP);
    f2b_kernel<<<(2 * N1 + 255) / 256, 256, 0, stream>>>(fc1_w,  w1, 2 * N1);
    f2b_kernel<<<(2 * N2 + 255) / 256, 256, 0, stream>>>(fc2_w,  w2, 2 * N2);
    bias_kernel<<<(921984 + 255) / 256, 256, 0, stream>>>(table, bmc);

    for (int i = 0; i < 2; ++i) {
        const int shifted = (i == 1);
        const float* xsrc = (i == 0) ? x : out;
        for (int c = 0; c < NC; ++c) {
            const int row_off = c * CR;
            const int widx_off = c * wpc;
            ln_kernel<<<CR / 4, 256, 0, stream>>>(
                xsrc, ln1_g + i * 192, ln1_b + i * 192, bufA, shifted ? 2 : 1, row_off);
            gemm_kernel<<<(CR / 128) * 6, 256, 0, stream>>>(
                bufA, wq + (size_t)i * NQ, qkv_b + i * 576,
                bufQ, nullptr, 576, 192, 0, 0, 0);
            attn_kernel<<<dim3(wpc, 6), 256, 0, stream>>>(
                bufQ, bmc + (size_t)i * 460992, bufA, shifted, widx_off);
            gemm_kernel<<<(CR / 128) * 2, 256, 0, stream>>>(
                bufA, wp + (size_t)i * NP, proj_b + i * 192,
                out, xsrc, 192, 192, 2, shifted, row_off);
        }
        for (int c = 0; c < NC; ++c) {
            const int row_off = c * CR;
            ln_kernel<<<CR / 4, 256, 0, stream>>>(
                out, ln2_g + i * 192, ln2_b + i * 192, bufA, 0, row_off);
            gemm_kernel<<<(CR / 128) * 8, 256, 0, stream>>>(
                bufA, w1 + (size_t)i * N1, fc1_b + i * 768,
                bufQ, nullptr, 768, 192, 1, 0, 0);
            gemm_kernel<<<(CR / 128) * 2, 256, 0, stream>>>(
                bufQ, w2 + (size_t)i * N2, fc2_b + i * 192,
                out + (size_t)row_off * 192, out + (size_t)row_off * 192,
                192, 768, 3, 0, 0);
        }
    }
}